// Round 2
// baseline (1517.814 us; speedup 1.0000x reference)
//
#include <hip/hip_runtime.h>
#include <math.h>

#define Bb 8
#define Nn 4096
#define Cc 512
#define Hh 8
#define Dd 64
#define Ff 128          // 2*D feature dim
#define M_ROWS (Bb * Nn)
#define QKV_LD (3 * Cc)
#define PI4f 0.78539816339744830962f
#define K1_CH 8               // row-chunks per (b,h)
#define K1_ROWS (Nn / K1_CH)  // 512 rows per K1 block
#define PART_STRIDE (Ff * Dd + Ff)  // 8320 floats per K1 partial

__device__ __forceinline__ float wsum64(float v) {
#pragma unroll
  for (int m = 32; m >= 1; m >>= 1) v += __shfl_xor(v, m, 64);
  return v;
}

// ============ K1: fused KV-GEMM + kf feature map + kv/ksum partial sums ============
// grid 512: h = bid/64, rem = bid%64, b = rem/8, chunk = rem%8 (bid%8==chunk -> XCD locality on x)
__global__ __launch_bounds__(256) void kv_kernel(
    const float* __restrict__ x, const float* __restrict__ w,
    const float* __restrict__ bias, float* __restrict__ part) {
  __shared__ float As[16][68];    // [k][m] x-tile, transposed store
  __shared__ float Bs[16][128];   // [k][j] weight strip (k-cols | v-cols)
  __shared__ float ksh[64][132];  // k|v output tile, 64 rows x (64 k + 64 v)
  __shared__ float kfb[4][128];   // 4 kf rows per batch
  const int t = threadIdx.x;
  const int lane = t & 63, wv = t >> 6;
  const int bid = blockIdx.x;
  const int h = bid >> 6;
  const int rem = bid & 63;
  const int b = rem >> 3, chunk = rem & 7;
  const int row0 = chunk * K1_ROWS;
  const int gx = t & 15, gy = t >> 4;
  const int jb = gx * 8;  // output col group 0..120
  const int colbase = (jb < 64) ? (Cc + h * 64 + jb) : (2 * Cc + h * 64 + (jb - 64));
  float bcol[8];
#pragma unroll
  for (int j = 0; j < 8; ++j) bcol[j] = bias[colbase + j];
  const int am = t >> 2, ak = (t & 3) * 4;
  const int f0 = gx * 8, d0 = gy * 4;
  float kvr[8][4] = {};
  float ksc = 0.f, kss = 0.f;

  for (int sub = 0; sub < K1_ROWS / 64; ++sub) {
    const int nA = b * Nn + row0 + sub * 64;
    float gacc[4][8] = {};
    for (int k0 = 0; k0 < Cc; k0 += 16) {
      float4 av = *(const float4*)&x[(size_t)(nA + am) * Cc + k0 + ak];
      float4 bv0 = *(const float4*)&w[(size_t)(k0 + gy) * QKV_LD + colbase];
      float4 bv1 = *(const float4*)&w[(size_t)(k0 + gy) * QKV_LD + colbase + 4];
      __syncthreads();  // previous iteration's LDS reads done
      As[ak + 0][am] = av.x;
      As[ak + 1][am] = av.y;
      As[ak + 2][am] = av.z;
      As[ak + 3][am] = av.w;
      *(float4*)&Bs[gy][jb] = bv0;
      *(float4*)&Bs[gy][jb + 4] = bv1;
      __syncthreads();
#pragma unroll
      for (int kk = 0; kk < 16; ++kk) {
        float4 a4 = *(const float4*)&As[kk][gy * 4];
        float4 b0 = *(const float4*)&Bs[kk][jb];
        float4 b1 = *(const float4*)&Bs[kk][jb + 4];
        float a[4] = {a4.x, a4.y, a4.z, a4.w};
        float bf[8] = {b0.x, b0.y, b0.z, b0.w, b1.x, b1.y, b1.z, b1.w};
#pragma unroll
        for (int i = 0; i < 4; ++i)
#pragma unroll
          for (int j = 0; j < 8; ++j) gacc[i][j] = fmaf(a[i], bf[j], gacc[i][j]);
      }
    }
    // write k|v tile (+bias) to ksh
#pragma unroll
    for (int i = 0; i < 4; ++i) {
      float4 o0 = {gacc[i][0] + bcol[0], gacc[i][1] + bcol[1],
                   gacc[i][2] + bcol[2], gacc[i][3] + bcol[3]};
      float4 o1 = {gacc[i][4] + bcol[4], gacc[i][5] + bcol[5],
                   gacc[i][6] + bcol[6], gacc[i][7] + bcol[7]};
      *(float4*)&ksh[gy * 4 + i][jb] = o0;
      *(float4*)&ksh[gy * 4 + i][jb + 4] = o1;
    }
    __syncthreads();
    // feature map + rank-4 accumulation, 4 rows per batch (one per wave)
    for (int bt = 0; bt < 16; ++bt) {
      const int r = bt * 4 + wv;
      float kx = ksh[r][lane];
      float nrm = sqrtf(wsum64(kx * kx));
      float dk = tanhf(kx / nrm * 20.0f) * PI4f;
      float a3 = fabsf(kx);
      a3 = a3 * a3 * a3;
      float sn, cs;
      sincosf(dk, &sn, &cs);
      float kc = a3 * cs, ks_ = a3 * sn;
      kfb[wv][lane] = kc;
      kfb[wv][64 + lane] = ks_;
      ksc += kc;
      kss += ks_;
      __syncthreads();
#pragma unroll
      for (int r2 = 0; r2 < 4; ++r2) {
        float4 a0 = *(const float4*)&kfb[r2][f0];
        float4 a1 = *(const float4*)&kfb[r2][f0 + 4];
        float4 bv = *(const float4*)&ksh[bt * 4 + r2][64 + d0];
        float af[8] = {a0.x, a0.y, a0.z, a0.w, a1.x, a1.y, a1.z, a1.w};
        float bf[4] = {bv.x, bv.y, bv.z, bv.w};
#pragma unroll
        for (int i = 0; i < 8; ++i)
#pragma unroll
          for (int j = 0; j < 4; ++j) kvr[i][j] = fmaf(af[i], bf[j], kvr[i][j]);
      }
      __syncthreads();
    }
  }
  // write partials (non-atomic)
  float* kvp = part + (size_t)bid * PART_STRIDE;
#pragma unroll
  for (int i = 0; i < 8; ++i)
#pragma unroll
    for (int j = 0; j < 4; ++j) kvp[(f0 + i) * Dd + d0 + j] = kvr[i][j];
  kfb[wv][lane] = ksc;
  kfb[wv][64 + lane] = kss;
  __syncthreads();
  if (t < Ff) kvp[Ff * Dd + t] = kfb[0][t] + kfb[1][t] + kfb[2][t] + kfb[3][t];
}

// ============ K1b: reduce partials -> kv (scaled 1/N) and k_mean ============
__global__ __launch_bounds__(256) void kv_reduce(const float* __restrict__ part,
                                                 float* __restrict__ kvacc,
                                                 float* __restrict__ ksum) {
  const int bh = blockIdx.x;
  const int b = bh >> 3, h = bh & 7;
  const float invN = 1.0f / Nn;
  const size_t base = (size_t)((h << 6) + (b << 3)) * PART_STRIDE;
  for (int i = threadIdx.x; i < Ff * Dd; i += 256) {
    float s = 0.f;
#pragma unroll
    for (int c = 0; c < K1_CH; ++c) s += part[base + (size_t)c * PART_STRIDE + i];
    kvacc[(size_t)bh * (Ff * Dd) + i] = s * invN;
  }
  if (threadIdx.x < Ff) {
    float s = 0.f;
#pragma unroll
    for (int c = 0; c < K1_CH; ++c)
      s += part[base + (size_t)c * PART_STRIDE + Ff * Dd + threadIdx.x];
    ksum[bh * Ff + threadIdx.x] = s * invN;
  }
}

// ============ K2: fused Q-GEMM + qf/z + PV matmul -> att (in d_out) ============
// grid 4096: h = bid/512, cg = bid%512, b = cg/64, n0 = (cg%64)*64
__global__ __launch_bounds__(256) void attn_kernel(
    const float* __restrict__ x, const float* __restrict__ w,
    const float* __restrict__ bias, const float* __restrict__ kvacc,
    const float* __restrict__ ksum, float* __restrict__ att) {
  __shared__ float sm[16384];   // 64 KB, overlaid regions
  float* qfs = sm;              // [64][128], XOR-swizzled, live stage2->4
  float* As = sm + 8192;        // [16][68] GEMM staging
  float* Bs = sm + 9280;        // [16][64]
  float* qsh = sm + 10304;      // [64][68] q tile
  float* kmean = sm + 14656;    // [128]
  float* kvs = sm + 8192;       // [128][64], stage 3+ (overlays As/Bs/qsh/kmean)
  const int t = threadIdx.x;
  const int lane = t & 63, wv = t >> 6;
  const int bid = blockIdx.x;
  const int h = bid >> 9;
  const int cg = bid & 511;
  const int b = cg >> 6;
  const int n0 = (cg & 63) * 64;
  const int bh = b * 8 + h;
  const int gx = t & 15, gy = t >> 4;
  if (t < Ff) kmean[t] = ksum[bh * Ff + t];
  // ---- q GEMM: 64 rows x 64 cols, K=512 ----
  const int am = t >> 2, ak = (t & 3) * 4;
  float qb[4];
#pragma unroll
  for (int j = 0; j < 4; ++j) qb[j] = bias[h * 64 + gx * 4 + j];
  float acc[4][4] = {};
  for (int k0 = 0; k0 < Cc; k0 += 16) {
    float4 av = *(const float4*)&x[(size_t)(b * Nn + n0 + am) * Cc + k0 + ak];
    float4 bv = *(const float4*)&w[(size_t)(k0 + gy) * QKV_LD + h * 64 + gx * 4];
    __syncthreads();
    As[(ak + 0) * 68 + am] = av.x;
    As[(ak + 1) * 68 + am] = av.y;
    As[(ak + 2) * 68 + am] = av.z;
    As[(ak + 3) * 68 + am] = av.w;
    *(float4*)&Bs[gy * 64 + gx * 4] = bv;
    __syncthreads();
#pragma unroll
    for (int kk = 0; kk < 16; ++kk) {
      float4 a4 = *(const float4*)&As[kk * 68 + gy * 4];
      float4 b4 = *(const float4*)&Bs[kk * 64 + gx * 4];
      float a[4] = {a4.x, a4.y, a4.z, a4.w};
      float bf[4] = {b4.x, b4.y, b4.z, b4.w};
#pragma unroll
      for (int i = 0; i < 4; ++i)
#pragma unroll
        for (int j = 0; j < 4; ++j) acc[i][j] = fmaf(a[i], bf[j], acc[i][j]);
    }
  }
  __syncthreads();
#pragma unroll
  for (int i = 0; i < 4; ++i) {
    float4 o = {acc[i][0] + qb[0], acc[i][1] + qb[1], acc[i][2] + qb[2],
                acc[i][3] + qb[3]};
    *(float4*)&qsh[(gy * 4 + i) * 68 + gx * 4] = o;
  }
  __syncthreads();
  // ---- qf feature map + z, write z*qf to qfs (swizzled) ----
  for (int rr = 0; rr < 16; ++rr) {
    const int r = wv * 16 + rr;
    float q = qsh[r * 68 + lane];
    float nrm = sqrtf(wsum64(q * q));
    float qt = q / nrm;
    float dq = tanhf(qt * 20.0f) * PI4f;
    float pw = 1.5f * (0.5f + tanhf(nrm));
    float qtp = powf(qt * qt, pw);
    float sn, cs;
    sincosf(dq, &sn, &cs);
    float qc = qtp * cs, qs_ = qtp * sn;
    float dot = wsum64(qc * kmean[lane] + qs_ * kmean[64 + lane]);
    float z = 1.0f / (dot + 1e-6f);
    const int sw = (r & 7) << 2;
    qfs[r * 128 + (lane ^ sw)] = qc * z;
    qfs[r * 128 + ((64 + lane) ^ sw)] = qs_ * z;
  }
  __syncthreads();
  for (int i = t; i < Ff * Dd; i += 256) kvs[i] = kvacc[(size_t)bh * (Ff * Dd) + i];
  __syncthreads();
  // ---- PV: (z*qf)[64x128] @ kv[128x64] ----
  float pacc[4][4] = {};
  const int r0 = gy * 4, dd0 = gx * 4;
#pragma unroll 4
  for (int f = 0; f < Ff; f += 4) {
    float bf[4][4];
#pragma unroll
    for (int jj = 0; jj < 4; ++jj) {
      float4 b4 = *(const float4*)&kvs[(f + jj) * Dd + dd0];
      bf[jj][0] = b4.x; bf[jj][1] = b4.y; bf[jj][2] = b4.z; bf[jj][3] = b4.w;
    }
#pragma unroll
    for (int i = 0; i < 4; ++i) {
      const int r = r0 + i;
      const int sw = (r & 7) << 2;
      float4 a4 = *(const float4*)&qfs[r * 128 + (f ^ sw)];
      float a[4] = {a4.x, a4.y, a4.z, a4.w};
#pragma unroll
      for (int jj = 0; jj < 4; ++jj)
#pragma unroll
        for (int j = 0; j < 4; ++j)
          pacc[i][j] = fmaf(a[jj], bf[jj][j], pacc[i][j]);
    }
  }
#pragma unroll
  for (int i = 0; i < 4; ++i) {
    float4 o = {pacc[i][0], pacc[i][1], pacc[i][2], pacc[i][3]};
    *(float4*)&att[(size_t)(b * Nn + n0 + r0 + i) * Cc + h * 64 + dd0] = o;
  }
}

// ============ in-place LayerNorm over C=512; one wave per row ============
__global__ __launch_bounds__(256) void ln_kernel(float* __restrict__ att,
                                                 const float* __restrict__ g,
                                                 const float* __restrict__ bta) {
  const int lane = threadIdx.x & 63, w = threadIdx.x >> 6;
  const size_t row = (size_t)blockIdx.x * 4 + w;
  float* p = att + row * Cc + lane * 8;
  float4 v0 = *(const float4*)p;
  float4 v1 = *(const float4*)(p + 4);
  float xv[8] = {v0.x, v0.y, v0.z, v0.w, v1.x, v1.y, v1.z, v1.w};
  float s = 0.f;
#pragma unroll
  for (int j = 0; j < 8; ++j) s += xv[j];
  s = wsum64(s);
  const float mu = s * (1.0f / Cc);
  float sq = 0.f;
#pragma unroll
  for (int j = 0; j < 8; ++j) {
    float d = xv[j] - mu;
    sq += d * d;
  }
  sq = wsum64(sq);
  const float rstd = rsqrtf(sq * (1.0f / Cc) + 1e-5f);
  const float4 g0 = *(const float4*)(g + lane * 8);
  const float4 g1 = *(const float4*)(g + lane * 8 + 4);
  const float4 b0 = *(const float4*)(bta + lane * 8);
  const float4 b1 = *(const float4*)(bta + lane * 8 + 4);
  float gg[8] = {g0.x, g0.y, g0.z, g0.w, g1.x, g1.y, g1.z, g1.w};
  float bb[8] = {b0.x, b0.y, b0.z, b0.w, b1.x, b1.y, b1.z, b1.w};
  float y[8];
#pragma unroll
  for (int j = 0; j < 8; ++j) y[j] = (xv[j] - mu) * rstd * gg[j] + bb[j];
  float4 o0 = {y[0], y[1], y[2], y[3]};
  float4 o1 = {y[4], y[5], y[6], y[7]};
  *(float4*)p = o0;
  *(float4*)(p + 4) = o1;
}

// ============ K3: in-place final GEMM on d_out: io = io @ w + bias ============
// 512 threads; block owns 64 full rows (all reads precede its writes).
__global__ __launch_bounds__(512) void out_gemm(float* __restrict__ io,
                                                const float* __restrict__ w,
                                                const float* __restrict__ bias) {
  __shared__ float As[8 * 68];   // [kk][row]
  __shared__ float Bs[8 * 516];  // [kk][col]
  const int t = threadIdx.x;
  const int m0 = blockIdx.x * 64;
  const int tx = t & 31, ty = t >> 5;  // rows ty*4+i, cols tx*4 + 128*j2
  const int ar = t >> 3, akk = t & 7;
  const int bk = t >> 6, bc0 = (t & 63) * 8;
  float acc[4][16] = {};
  for (int k0 = 0; k0 < Cc; k0 += 8) {
    float a_in = io[(size_t)(m0 + ar) * Cc + k0 + akk];
    float4 b0 = *(const float4*)&w[(size_t)(k0 + bk) * Cc + bc0];
    float4 b1 = *(const float4*)&w[(size_t)(k0 + bk) * Cc + bc0 + 4];
    __syncthreads();
    As[akk * 68 + ar] = a_in;
    *(float4*)&Bs[bk * 516 + bc0] = b0;
    *(float4*)&Bs[bk * 516 + bc0 + 4] = b1;
    __syncthreads();
#pragma unroll
    for (int kk = 0; kk < 8; ++kk) {
      float4 av = *(const float4*)&As[kk * 68 + ty * 4];
      float a[4] = {av.x, av.y, av.z, av.w};
#pragma unroll
      for (int j2 = 0; j2 < 4; ++j2) {
        float4 bv = *(const float4*)&Bs[kk * 516 + tx * 4 + 128 * j2];
        float bf[4] = {bv.x, bv.y, bv.z, bv.w};
#pragma unroll
        for (int i = 0; i < 4; ++i)
#pragma unroll
          for (int j = 0; j < 4; ++j)
            acc[i][j2 * 4 + j] = fmaf(a[i], bf[j], acc[i][j2 * 4 + j]);
      }
    }
  }
#pragma unroll
  for (int j2 = 0; j2 < 4; ++j2) {
    float4 bb = *(const float4*)&bias[tx * 4 + 128 * j2];
    float bf[4] = {bb.x, bb.y, bb.z, bb.w};
#pragma unroll
    for (int i = 0; i < 4; ++i) {
      float4 o = {acc[i][j2 * 4 + 0] + bf[0], acc[i][j2 * 4 + 1] + bf[1],
                  acc[i][j2 * 4 + 2] + bf[2], acc[i][j2 * 4 + 3] + bf[3]};
      *(float4*)&io[(size_t)(m0 + ty * 4 + i) * Cc + tx * 4 + 128 * j2] = o;
    }
  }
}

extern "C" void kernel_launch(void* const* d_in, const int* in_sizes, int n_in,
                              void* d_out, int out_size, void* d_ws,
                              size_t ws_size, hipStream_t stream) {
  const float* x = (const float*)d_in[0];
  const float* qkv_w = (const float*)d_in[1];
  const float* qkv_b = (const float*)d_in[2];
  const float* ln_g = (const float*)d_in[3];
  const float* ln_b = (const float*)d_in[4];
  const float* out_w = (const float*)d_in[5];
  const float* out_b = (const float*)d_in[6];
  float* out = (float*)d_out;

  float* ws = (float*)d_ws;
  float* part = ws;                                  // 512 * 8320 floats (~17 MB)
  float* kvacc = part + (size_t)512 * PART_STRIDE;   // 64*128*64 floats (2 MB)
  float* ksum = kvacc + (size_t)64 * Ff * Dd;        // 64*128 floats

  kv_kernel<<<512, 256, 0, stream>>>(x, qkv_w, qkv_b, part);
  kv_reduce<<<64, 256, 0, stream>>>(part, kvacc, ksum);
  attn_kernel<<<4096, 256, 0, stream>>>(x, qkv_w, qkv_b, kvacc, ksum, out);
  ln_kernel<<<M_ROWS / 4, 256, 0, stream>>>(out, ln_g, ln_b);
  out_gemm<<<M_ROWS / 64, 512, 0, stream>>>(out, out_w, out_b);
}

// Round 3
// 617.993 us; speedup vs baseline: 2.4560x; 2.4560x over previous
//
#include <hip/hip_runtime.h>
#include <math.h>

#define Bb 8
#define Nn 4096
#define Cc 512
#define Hh 8
#define Dd 64
#define Ff 128
#define M_ROWS (Bb * Nn)
#define PI4f 0.78539816339744830962f
#define CHB 16
#define PART 8320  // 128*64 kv + 128 ksum

using bf16x8 = __attribute__((ext_vector_type(8))) short;
using f32x4 = __attribute__((ext_vector_type(4))) float;

__device__ __forceinline__ unsigned short f2bf(float f) {
  unsigned u = __float_as_uint(f);
  u += 0x7FFFu + ((u >> 16) & 1u);
  return (unsigned short)(u >> 16);
}
__device__ __forceinline__ float bf2f(unsigned short h) {
  return __uint_as_float(((unsigned)h) << 16);
}
__device__ __forceinline__ float grp16_sum(float v) {
  v += __shfl_xor(v, 1);
  v += __shfl_xor(v, 2);
  v += __shfl_xor(v, 4);
  v += __shfl_xor(v, 8);
  return v;
}
__device__ __forceinline__ float wsum64(float v) {
#pragma unroll
  for (int m = 32; m >= 1; m >>= 1) v += __shfl_xor(v, m, 64);
  return v;
}

// ============ convert x (fp32 -> bf16), 8192 blocks ============
__global__ __launch_bounds__(256) void x_convert(const float* __restrict__ x,
                                                 unsigned short* __restrict__ xb) {
  size_t i = ((size_t)blockIdx.x * 256 + threadIdx.x) * 8;
  float4 a = *(const float4*)(x + i);
  float4 b = *(const float4*)(x + i + 4);
  int4 o;
  o.x = (int)f2bf(a.x) | ((int)f2bf(a.y) << 16);
  o.y = (int)f2bf(a.z) | ((int)f2bf(a.w) << 16);
  o.z = (int)f2bf(b.x) | ((int)f2bf(b.y) << 16);
  o.w = (int)f2bf(b.z) | ((int)f2bf(b.w) << 16);
  *(int4*)(xb + i) = o;
}

// ============ transpose qkv_w (512x1536) and out_w (512x512) -> bf16 [col][k] ============
__global__ __launch_bounds__(256) void w_transpose(const float* __restrict__ qkvw,
                                                   const float* __restrict__ outw,
                                                   unsigned short* __restrict__ wt,
                                                   unsigned short* __restrict__ owt) {
  __shared__ float tile[64][65];
  const int bid = blockIdx.x;
  const float* src;
  unsigned short* dst;
  int ldsrc, j0, k0;
  if (bid < 192) {
    src = qkvw; dst = wt; ldsrc = 1536;
    j0 = (bid % 24) * 64; k0 = (bid / 24) * 64;
  } else {
    int r = bid - 192;
    src = outw; dst = owt; ldsrc = 512;
    j0 = (r & 7) * 64; k0 = (r >> 3) * 64;
  }
  const int t = threadIdx.x;
  const int rr = t >> 4, cc = (t & 15) * 4;
#pragma unroll
  for (int it = 0; it < 4; ++it) {
    float4 v = *(const float4*)(src + (size_t)(k0 + rr + it * 16) * ldsrc + j0 + cc);
    tile[rr + it * 16][cc + 0] = v.x;
    tile[rr + it * 16][cc + 1] = v.y;
    tile[rr + it * 16][cc + 2] = v.z;
    tile[rr + it * 16][cc + 3] = v.w;
  }
  __syncthreads();
  const int j = t >> 2, kq = (t & 3) * 16;
  unsigned short u[16];
#pragma unroll
  for (int p = 0; p < 16; ++p) u[p] = f2bf(tile[kq + p][j]);
  int4 o;
  o.x = (int)u[0] | ((int)u[1] << 16);
  o.y = (int)u[2] | ((int)u[3] << 16);
  o.z = (int)u[4] | ((int)u[5] << 16);
  o.w = (int)u[6] | ((int)u[7] << 16);
  int4 o2;
  o2.x = (int)u[8] | ((int)u[9] << 16);
  o2.y = (int)u[10] | ((int)u[11] << 16);
  o2.z = (int)u[12] | ((int)u[13] << 16);
  o2.w = (int)u[14] | ((int)u[15] << 16);
  *(int4*)(dst + (size_t)(j0 + j) * 512 + k0 + kq) = o;
  *(int4*)(dst + (size_t)(j0 + j) * 512 + k0 + kq + 8) = o2;
}

// ============ K1: fused KV-GEMM (MFMA) + feature map + kv/ksum partials ============
// grid 1024: bh = bid>>4, chunk = bid&15 (256 rows each)
__global__ __launch_bounds__(256) void kv_kernel(const unsigned short* __restrict__ xb,
                                                 const unsigned short* __restrict__ wt,
                                                 const float* __restrict__ qkvb,
                                                 float* __restrict__ part) {
  __shared__ unsigned short kf_t[128 * 72];  // [f][n] bf16, LD=72
  __shared__ unsigned short v_t[64 * 72];    // [d][n] bf16
  __shared__ float ksl[4][128];
  const int t = threadIdx.x, lane = t & 63, wv = t >> 6;
  const int i = lane & 15, g = lane >> 4, kq = g * 8;
  const int bid = blockIdx.x;
  const int bh = bid >> 4, chunk = bid & 15;
  const int b = bh >> 3, h = bh & 7;
  const size_t rowchunk = (size_t)b * Nn + chunk * 256;
  int colj[8];
#pragma unroll
  for (int j = 0; j < 8; ++j)
    colj[j] = (j < 4) ? (Cc + h * 64 + 16 * j) : (2 * Cc + h * 64 + 16 * (j - 4));
  float bq[8];
#pragma unroll
  for (int j = 0; j < 8; ++j) bq[j] = qkvb[colj[j] + i];
  const unsigned short* bp0 = wt + (size_t)(colj[0] + i) * 512 + kq;
  const unsigned short* bp1 = wt + (size_t)(colj[1] + i) * 512 + kq;
  const unsigned short* bp2 = wt + (size_t)(colj[2] + i) * 512 + kq;
  const unsigned short* bp3 = wt + (size_t)(colj[3] + i) * 512 + kq;
  const unsigned short* bp4 = wt + (size_t)(colj[4] + i) * 512 + kq;
  const unsigned short* bp5 = wt + (size_t)(colj[5] + i) * 512 + kq;
  const unsigned short* bp6 = wt + (size_t)(colj[6] + i) * 512 + kq;
  const unsigned short* bp7 = wt + (size_t)(colj[7] + i) * 512 + kq;

  f32x4 kvf[2][4] = {};
  float ksc[4] = {0.f, 0.f, 0.f, 0.f}, kss[4] = {0.f, 0.f, 0.f, 0.f};

  for (int t4 = 0; t4 < 4; ++t4) {
    const unsigned short* ap =
        xb + (rowchunk + t4 * 64 + 16 * wv + i) * 512 + kq;
    f32x4 acc[8] = {};
#pragma unroll 2
    for (int k0 = 0; k0 < 512; k0 += 32) {
      bf16x8 af = *(const bf16x8*)(ap + k0);
      acc[0] = __builtin_amdgcn_mfma_f32_16x16x32_bf16(af, *(const bf16x8*)(bp0 + k0), acc[0], 0, 0, 0);
      acc[1] = __builtin_amdgcn_mfma_f32_16x16x32_bf16(af, *(const bf16x8*)(bp1 + k0), acc[1], 0, 0, 0);
      acc[2] = __builtin_amdgcn_mfma_f32_16x16x32_bf16(af, *(const bf16x8*)(bp2 + k0), acc[2], 0, 0, 0);
      acc[3] = __builtin_amdgcn_mfma_f32_16x16x32_bf16(af, *(const bf16x8*)(bp3 + k0), acc[3], 0, 0, 0);
      acc[4] = __builtin_amdgcn_mfma_f32_16x16x32_bf16(af, *(const bf16x8*)(bp4 + k0), acc[4], 0, 0, 0);
      acc[5] = __builtin_amdgcn_mfma_f32_16x16x32_bf16(af, *(const bf16x8*)(bp5 + k0), acc[5], 0, 0, 0);
      acc[6] = __builtin_amdgcn_mfma_f32_16x16x32_bf16(af, *(const bf16x8*)(bp6 + k0), acc[6], 0, 0, 0);
      acc[7] = __builtin_amdgcn_mfma_f32_16x16x32_bf16(af, *(const bf16x8*)(bp7 + k0), acc[7], 0, 0, 0);
    }
#pragma unroll
    for (int j = 0; j < 8; ++j)
#pragma unroll
      for (int r = 0; r < 4; ++r) acc[j][r] += bq[j];
    // row norms (rows 4g+r of this wave's 16-row set)
    float nrm[4];
#pragma unroll
    for (int r = 0; r < 4; ++r) {
      float s = acc[0][r] * acc[0][r] + acc[1][r] * acc[1][r] +
                acc[2][r] * acc[2][r] + acc[3][r] * acc[3][r];
      nrm[r] = sqrtf(grp16_sum(s));
    }
    const int nloc = 16 * wv + 4 * g;
#pragma unroll
    for (int j = 0; j < 4; ++j)
#pragma unroll
      for (int r = 0; r < 4; ++r) {
        float kx = acc[j][r];
        float dk = tanhf(kx / nrm[r] * 20.0f) * PI4f;
        float a3 = fabsf(kx);
        a3 = a3 * a3 * a3;
        float sn, cs;
        __sincosf(dk, &sn, &cs);
        float kc = a3 * cs, ksn = a3 * sn;
        ksc[j] += kc;
        kss[j] += ksn;
        kf_t[(16 * j + i) * 72 + nloc + r] = f2bf(kc);
        kf_t[(64 + 16 * j + i) * 72 + nloc + r] = f2bf(ksn);
      }
#pragma unroll
    for (int j = 4; j < 8; ++j)
#pragma unroll
      for (int r = 0; r < 4; ++r)
        v_t[(16 * (j - 4) + i) * 72 + nloc + r] = f2bf(acc[j][r]);
    __syncthreads();
    // kv += kf^T @ v over this 64-row tile (K=64)
#pragma unroll
    for (int ks = 0; ks < 2; ++ks) {
      bf16x8 a0 = *(const bf16x8*)&kf_t[(16 * (2 * wv + 0) + i) * 72 + ks * 32 + kq];
      bf16x8 a1 = *(const bf16x8*)&kf_t[(16 * (2 * wv + 1) + i) * 72 + ks * 32 + kq];
#pragma unroll
      for (int nt = 0; nt < 4; ++nt) {
        bf16x8 bv = *(const bf16x8*)&v_t[(16 * nt + i) * 72 + ks * 32 + kq];
        kvf[0][nt] = __builtin_amdgcn_mfma_f32_16x16x32_bf16(a0, bv, kvf[0][nt], 0, 0, 0);
        kvf[1][nt] = __builtin_amdgcn_mfma_f32_16x16x32_bf16(a1, bv, kvf[1][nt], 0, 0, 0);
      }
    }
    __syncthreads();
  }
  float* pw = part + (size_t)bid * PART;
#pragma unroll
  for (int m2 = 0; m2 < 2; ++m2)
#pragma unroll
    for (int nt = 0; nt < 4; ++nt)
#pragma unroll
      for (int r = 0; r < 4; ++r)
        pw[(16 * (2 * wv + m2) + 4 * g + r) * 64 + 16 * nt + i] = kvf[m2][nt][r];
#pragma unroll
  for (int j = 0; j < 4; ++j) {
    float c = ksc[j];
    c += __shfl_xor(c, 16);
    c += __shfl_xor(c, 32);
    float s = kss[j];
    s += __shfl_xor(s, 16);
    s += __shfl_xor(s, 32);
    if (lane < 16) {
      ksl[wv][16 * j + lane] = c;
      ksl[wv][64 + 16 * j + lane] = s;
    }
  }
  __syncthreads();
  if (t < 128) pw[8192 + t] = ksl[0][t] + ksl[1][t] + ksl[2][t] + ksl[3][t];
}

// ============ K1b: reduce partials -> kv^T bf16 [bh][d][f] and k_mean fp32 ============
__global__ __launch_bounds__(256) void kv_reduce(const float* __restrict__ part,
                                                 unsigned short* __restrict__ kvt,
                                                 float* __restrict__ kmean) {
  const int bh = blockIdx.x;
  const float invN = 1.0f / Nn;
  const size_t base = (size_t)bh * CHB * PART;
  for (int idx = threadIdx.x; idx < 8192; idx += 256) {
    float s = 0.f;
#pragma unroll
    for (int c = 0; c < CHB; ++c) s += part[base + (size_t)c * PART + idx];
    int f = idx >> 6, d = idx & 63;
    kvt[(size_t)bh * 8192 + d * 128 + f] = f2bf(s * invN);
  }
  if (threadIdx.x < 128) {
    float s = 0.f;
#pragma unroll
    for (int c = 0; c < CHB; ++c) s += part[base + (size_t)c * PART + 8192 + threadIdx.x];
    kmean[bh * 128 + threadIdx.x] = s * invN;
  }
}

// ============ K2: fused Q-GEMM (MFMA) + qf/z + PV (MFMA) -> att bf16 ============
// grid 4096: bh = bid>>6, chunk = bid&63 (64 rows)
__global__ __launch_bounds__(256) void attn_kernel(const unsigned short* __restrict__ xb,
                                                   const unsigned short* __restrict__ wt,
                                                   const float* __restrict__ qkvb,
                                                   const unsigned short* __restrict__ kvt,
                                                   const float* __restrict__ kmean,
                                                   unsigned short* __restrict__ attb) {
  __shared__ unsigned short qf_t[64 * 136];  // [n][f] bf16, LD=136
  __shared__ unsigned short kv_s[64 * 136];  // [d][f] bf16
  __shared__ float km[128];
  const int t = threadIdx.x, lane = t & 63, wv = t >> 6;
  const int i = lane & 15, g = lane >> 4, kq = g * 8;
  const int bid = blockIdx.x;
  const int bh = bid >> 6, chunk = bid & 63;
  const int b = bh >> 3, h = bh & 7;
  const size_t row0 = (size_t)b * Nn + chunk * 64;
  if (t < 128) km[t] = kmean[bh * 128 + t];
  {
    const unsigned short* src = kvt + (size_t)bh * 8192;
#pragma unroll
    for (int it = 0; it < 4; ++it) {
      int idx = t + it * 256;
      int d = idx >> 4, f8 = (idx & 15) * 8;
      *(bf16x8*)&kv_s[d * 136 + f8] = *(const bf16x8*)(src + d * 128 + f8);
    }
  }
  float bqv[4];
#pragma unroll
  for (int j = 0; j < 4; ++j) bqv[j] = qkvb[h * 64 + 16 * j + i];
  f32x4 acc[4] = {};
  const unsigned short* ap = xb + (row0 + 16 * wv + i) * 512 + kq;
  const unsigned short* qp0 = wt + (size_t)(h * 64 + 16 * 0 + i) * 512 + kq;
  const unsigned short* qp1 = wt + (size_t)(h * 64 + 16 * 1 + i) * 512 + kq;
  const unsigned short* qp2 = wt + (size_t)(h * 64 + 16 * 2 + i) * 512 + kq;
  const unsigned short* qp3 = wt + (size_t)(h * 64 + 16 * 3 + i) * 512 + kq;
#pragma unroll 2
  for (int k0 = 0; k0 < 512; k0 += 32) {
    bf16x8 af = *(const bf16x8*)(ap + k0);
    acc[0] = __builtin_amdgcn_mfma_f32_16x16x32_bf16(af, *(const bf16x8*)(qp0 + k0), acc[0], 0, 0, 0);
    acc[1] = __builtin_amdgcn_mfma_f32_16x16x32_bf16(af, *(const bf16x8*)(qp1 + k0), acc[1], 0, 0, 0);
    acc[2] = __builtin_amdgcn_mfma_f32_16x16x32_bf16(af, *(const bf16x8*)(qp2 + k0), acc[2], 0, 0, 0);
    acc[3] = __builtin_amdgcn_mfma_f32_16x16x32_bf16(af, *(const bf16x8*)(qp3 + k0), acc[3], 0, 0, 0);
  }
  __syncthreads();  // staging (kv_s, km) complete
  float z[4], nrm[4];
#pragma unroll
  for (int r = 0; r < 4; ++r) {
    float s = 0.f;
#pragma unroll
    for (int j = 0; j < 4; ++j) {
      float q = acc[j][r] + bqv[j];
      s += q * q;
    }
    nrm[r] = sqrtf(grp16_sum(s));
  }
  const int nloc = 16 * wv + 4 * g;
#pragma unroll
  for (int r = 0; r < 4; ++r) {
    float dp = 0.f;
    float pw = 1.5f * (0.5f + tanhf(nrm[r]));
#pragma unroll
    for (int j = 0; j < 4; ++j) {
      float q = acc[j][r] + bqv[j];
      float qt = q / nrm[r];
      float dq = tanhf(qt * 20.0f) * PI4f;
      float qtp = exp2f(pw * __log2f(qt * qt));
      float sn, cs;
      __sincosf(dq, &sn, &cs);
      float qc = qtp * cs, qs = qtp * sn;
      dp += qc * km[16 * j + i] + qs * km[64 + 16 * j + i];
      qf_t[(nloc + r) * 136 + 16 * j + i] = f2bf(qc);
      qf_t[(nloc + r) * 136 + 64 + 16 * j + i] = f2bf(qs);
    }
    dp = grp16_sum(dp);
    z[r] = 1.0f / (dp + 1e-6f);
  }
  __syncthreads();
  f32x4 pacc[4] = {};
#pragma unroll
  for (int ks = 0; ks < 4; ++ks) {
    bf16x8 a = *(const bf16x8*)&qf_t[(16 * wv + i) * 136 + ks * 32 + kq];
#pragma unroll
    for (int nt = 0; nt < 4; ++nt) {
      bf16x8 bv = *(const bf16x8*)&kv_s[(16 * nt + i) * 136 + ks * 32 + kq];
      pacc[nt] = __builtin_amdgcn_mfma_f32_16x16x32_bf16(a, bv, pacc[nt], 0, 0, 0);
    }
  }
#pragma unroll
  for (int nt = 0; nt < 4; ++nt)
#pragma unroll
    for (int r = 0; r < 4; ++r)
      attb[(row0 + nloc + r) * 512 + h * 64 + 16 * nt + i] =
          f2bf(pacc[nt][r] * z[r]);
}

// ============ in-place LayerNorm on bf16 att ============
__global__ __launch_bounds__(256) void ln_kernel(unsigned short* __restrict__ attb,
                                                 const float* __restrict__ gg,
                                                 const float* __restrict__ bb) {
  const int lane = threadIdx.x & 63, wv = threadIdx.x >> 6;
  const size_t row = (size_t)blockIdx.x * 4 + wv;
  unsigned short* p = attb + row * 512 + lane * 8;
  bf16x8 v = *(bf16x8*)p;
  float x[8];
#pragma unroll
  for (int j = 0; j < 8; ++j) x[j] = bf2f((unsigned short)v[j]);
  float s = 0.f;
#pragma unroll
  for (int j = 0; j < 8; ++j) s += x[j];
  const float mu = wsum64(s) * (1.0f / 512.0f);
  float sq = 0.f;
#pragma unroll
  for (int j = 0; j < 8; ++j) {
    float d = x[j] - mu;
    sq += d * d;
  }
  const float rstd = rsqrtf(wsum64(sq) * (1.0f / 512.0f) + 1e-5f);
  const float4 g0 = *(const float4*)(gg + lane * 8);
  const float4 g1 = *(const float4*)(gg + lane * 8 + 4);
  const float4 b0 = *(const float4*)(bb + lane * 8);
  const float4 b1 = *(const float4*)(bb + lane * 8 + 4);
  float gv[8] = {g0.x, g0.y, g0.z, g0.w, g1.x, g1.y, g1.z, g1.w};
  float bv[8] = {b0.x, b0.y, b0.z, b0.w, b1.x, b1.y, b1.z, b1.w};
#pragma unroll
  for (int j = 0; j < 8; ++j)
    v[j] = (short)f2bf((x[j] - mu) * rstd * gv[j] + bv[j]);
  *(bf16x8*)p = v;
}

// ============ K3: final GEMM (bf16 MFMA): out = ln_att @ out_w + bias ============
// 128x128 tiles, BK=64, 2-phase reg prefetch. grid 1024.
__global__ __launch_bounds__(256) void out_gemm(const unsigned short* __restrict__ attb,
                                                const unsigned short* __restrict__ owt,
                                                const float* __restrict__ ob,
                                                float* __restrict__ outp) {
  __shared__ unsigned short As[128 * 72];
  __shared__ unsigned short Bs[128 * 72];
  const int t = threadIdx.x, lane = t & 63, wv = t >> 6;
  const int i = lane & 15, g = lane >> 4, kq = g * 8;
  const int wm = wv >> 1, wn = wv & 1;
  const int m0 = (blockIdx.x >> 2) * 128, n0 = (blockIdx.x & 3) * 128;
  const int sr = t >> 1, sko = (t & 1) * 32;
  const unsigned short* ag = attb + (size_t)(m0 + sr) * 512 + sko;
  const unsigned short* bg = owt + (size_t)(n0 + sr) * 512 + sko;
  f32x4 acc[4][4] = {};
  bf16x8 pa[4], pb[4];
#pragma unroll
  for (int p = 0; p < 4; ++p) {
    pa[p] = *(const bf16x8*)(ag + p * 8);
    pb[p] = *(const bf16x8*)(bg + p * 8);
  }
  for (int k0 = 0; k0 < 512; k0 += 64) {
    __syncthreads();
#pragma unroll
    for (int p = 0; p < 4; ++p) {
      *(bf16x8*)&As[sr * 72 + sko + p * 8] = pa[p];
      *(bf16x8*)&Bs[sr * 72 + sko + p * 8] = pb[p];
    }
    __syncthreads();
    if (k0 < 448) {
#pragma unroll
      for (int p = 0; p < 4; ++p) {
        pa[p] = *(const bf16x8*)(ag + k0 + 64 + p * 8);
        pb[p] = *(const bf16x8*)(bg + k0 + 64 + p * 8);
      }
    }
#pragma unroll
    for (int ks = 0; ks < 2; ++ks) {
      bf16x8 am[4], bn[4];
#pragma unroll
      for (int q = 0; q < 4; ++q) {
        am[q] = *(const bf16x8*)&As[(64 * wm + 16 * q + i) * 72 + ks * 32 + kq];
        bn[q] = *(const bf16x8*)&Bs[(64 * wn + 16 * q + i) * 72 + ks * 32 + kq];
      }
#pragma unroll
      for (int mi = 0; mi < 4; ++mi)
#pragma unroll
        for (int ni = 0; ni < 4; ++ni)
          acc[mi][ni] = __builtin_amdgcn_mfma_f32_16x16x32_bf16(am[mi], bn[ni], acc[mi][ni], 0, 0, 0);
    }
  }
#pragma unroll
  for (int ni = 0; ni < 4; ++ni) {
    float bv = ob[n0 + 64 * wn + 16 * ni + i];
#pragma unroll
    for (int mi = 0; mi < 4; ++mi)
#pragma unroll
      for (int r = 0; r < 4; ++r)
        outp[(size_t)(m0 + 64 * wm + 16 * mi + 4 * g + r) * 512 + n0 + 64 * wn +
             16 * ni + i] = acc[mi][ni][r] + bv;
  }
}

extern "C" void kernel_launch(void* const* d_in, const int* in_sizes, int n_in,
                              void* d_out, int out_size, void* d_ws,
                              size_t ws_size, hipStream_t stream) {
  const float* x = (const float*)d_in[0];
  const float* qkv_w = (const float*)d_in[1];
  const float* qkv_b = (const float*)d_in[2];
  const float* ln_g = (const float*)d_in[3];
  const float* ln_b = (const float*)d_in[4];
  const float* out_w = (const float*)d_in[5];
  const float* out_b = (const float*)d_in[6];
  float* out = (float*)d_out;

  char* w = (char*)d_ws;
  unsigned short* xb = (unsigned short*)w;                    // 33,554,432 B
  unsigned short* wt = (unsigned short*)(w + 33554432);       // 1,572,864 B
  unsigned short* owt = (unsigned short*)(w + 35127296);      // 524,288 B
  unsigned short* kvt = (unsigned short*)(w + 35651584);      // 1,048,576 B
  float* kmean = (float*)(w + 36700160);                      // 32,768 B
  char* R = w + 36732928;
  float* part = (float*)R;            // 1024*8320*4 = 34,078,720 B
  unsigned short* attb = (unsigned short*)R;  // 33,554,432 B (aliases part; part is dead by then)

  x_convert<<<8192, 256, 0, stream>>>(x, xb);
  w_transpose<<<256, 256, 0, stream>>>(qkv_w, out_w, wt, owt);
  kv_kernel<<<1024, 256, 0, stream>>>(xb, wt, qkv_b, part);
  kv_reduce<<<64, 256, 0, stream>>>(part, kvt, kmean);
  attn_kernel<<<4096, 256, 0, stream>>>(xb, wt, qkv_b, kvt, kmean, attb);
  ln_kernel<<<8192, 256, 0, stream>>>(attb, ln_g, ln_b);
  out_gemm<<<1024, 256, 0, stream>>>(attb, owt, out_b, out);
}

// Round 4
// 399.523 us; speedup vs baseline: 3.7991x; 1.5468x over previous
//
#include <hip/hip_runtime.h>
#include <math.h>

#define Bb 8
#define Nn 4096
#define Cc 512
#define Hh 8
#define Dd 64
#define Ff 128
#define M_ROWS (Bb * Nn)
#define PI4f 0.78539816339744830962f
#define CHB 16
#define PART 8320  // 128*64 kv + 128 ksum

using bf16x8 = __attribute__((ext_vector_type(8))) short;
using f32x4 = __attribute__((ext_vector_type(4))) float;

__device__ __forceinline__ unsigned short f2bf(float f) {
  unsigned u = __float_as_uint(f);
  u += 0x7FFFu + ((u >> 16) & 1u);
  return (unsigned short)(u >> 16);
}
__device__ __forceinline__ float bf2f(unsigned short h) {
  return __uint_as_float(((unsigned)h) << 16);
}
__device__ __forceinline__ float grp16_sum(float v) {
  v += __shfl_xor(v, 1);
  v += __shfl_xor(v, 2);
  v += __shfl_xor(v, 4);
  v += __shfl_xor(v, 8);
  return v;
}
__device__ __forceinline__ float wsum64(float v) {
#pragma unroll
  for (int m = 32; m >= 1; m >>= 1) v += __shfl_xor(v, m, 64);
  return v;
}

// ============ convert x (fp32 -> bf16), 8192 blocks ============
__global__ __launch_bounds__(256) void x_convert(const float* __restrict__ x,
                                                 unsigned short* __restrict__ xb) {
  size_t i = ((size_t)blockIdx.x * 256 + threadIdx.x) * 8;
  float4 a = *(const float4*)(x + i);
  float4 b = *(const float4*)(x + i + 4);
  int4 o;
  o.x = (int)f2bf(a.x) | ((int)f2bf(a.y) << 16);
  o.y = (int)f2bf(a.z) | ((int)f2bf(a.w) << 16);
  o.z = (int)f2bf(b.x) | ((int)f2bf(b.y) << 16);
  o.w = (int)f2bf(b.z) | ((int)f2bf(b.w) << 16);
  *(int4*)(xb + i) = o;
}

// ============ transpose qkv_w (512x1536) and out_w (512x512) -> bf16 [col][k] ============
__global__ __launch_bounds__(256) void w_transpose(const float* __restrict__ qkvw,
                                                   const float* __restrict__ outw,
                                                   unsigned short* __restrict__ wt,
                                                   unsigned short* __restrict__ owt) {
  __shared__ float tile[64][65];
  const int bid = blockIdx.x;
  const float* src;
  unsigned short* dst;
  int ldsrc, j0, k0;
  if (bid < 192) {
    src = qkvw; dst = wt; ldsrc = 1536;
    j0 = (bid % 24) * 64; k0 = (bid / 24) * 64;
  } else {
    int r = bid - 192;
    src = outw; dst = owt; ldsrc = 512;
    j0 = (r & 7) * 64; k0 = (r >> 3) * 64;
  }
  const int t = threadIdx.x;
  const int rr = t >> 4, cc = (t & 15) * 4;
#pragma unroll
  for (int it = 0; it < 4; ++it) {
    float4 v = *(const float4*)(src + (size_t)(k0 + rr + it * 16) * ldsrc + j0 + cc);
    tile[rr + it * 16][cc + 0] = v.x;
    tile[rr + it * 16][cc + 1] = v.y;
    tile[rr + it * 16][cc + 2] = v.z;
    tile[rr + it * 16][cc + 3] = v.w;
  }
  __syncthreads();
  const int j = t >> 2, kq = (t & 3) * 16;
  unsigned short u[16];
#pragma unroll
  for (int p = 0; p < 16; ++p) u[p] = f2bf(tile[kq + p][j]);
  int4 o;
  o.x = (int)u[0] | ((int)u[1] << 16);
  o.y = (int)u[2] | ((int)u[3] << 16);
  o.z = (int)u[4] | ((int)u[5] << 16);
  o.w = (int)u[6] | ((int)u[7] << 16);
  int4 o2;
  o2.x = (int)u[8] | ((int)u[9] << 16);
  o2.y = (int)u[10] | ((int)u[11] << 16);
  o2.z = (int)u[12] | ((int)u[13] << 16);
  o2.w = (int)u[14] | ((int)u[15] << 16);
  *(int4*)(dst + (size_t)(j0 + j) * 512 + k0 + kq) = o;
  *(int4*)(dst + (size_t)(j0 + j) * 512 + k0 + kq + 8) = o2;
}

// ============ K1: fused KV-GEMM (LDS-staged MFMA) + feature map + kv/ksum partials ============
// grid 1024: bh = bid>>4, chunk = bid&15 (256 rows = 2 tiles of 128)
__global__ __launch_bounds__(256) void kv_kernel(const unsigned short* __restrict__ xb,
                                                 const unsigned short* __restrict__ wt,
                                                 const float* __restrict__ qkvb,
                                                 float* __restrict__ part) {
  __shared__ char smraw[53248];
  unsigned short* As = (unsigned short*)smraw;              // [128][72] (GEMM phase)
  unsigned short* Bs = As + 128 * 72;                       // [128][72]
  unsigned short* kf_t = (unsigned short*)smraw;            // [128][136] (epilogue, overlays As/Bs)
  unsigned short* v_t = kf_t + 128 * 136;                   // [64][136]
  float* ksl = (float*)(smraw + 52224);                     // [2][128]
  const int t = threadIdx.x, lane = t & 63, wv = t >> 6;
  const int i = lane & 15, g = lane >> 4, kq = g * 8;
  const int wm = wv >> 1, wn = wv & 1;
  const int bh = blockIdx.x >> 4, chunk = blockIdx.x & 15;
  const int b = bh >> 3, h = bh & 7;
  const int sr = t >> 1, sko = (t & 1) * 32;
  const int wrow = (sr < 64) ? (512 + h * 64 + sr) : (1024 + h * 64 + sr - 64);
  const unsigned short* bg = wt + (size_t)wrow * 512 + sko;
  float bias_[4];
  const int cb = ((wn == 0) ? 512 : 1024) + h * 64 + i;
#pragma unroll
  for (int ni = 0; ni < 4; ++ni) bias_[ni] = qkvb[cb + 16 * ni];
  f32x4 kvf[4][2] = {};
  float ksc[4] = {0.f, 0.f, 0.f, 0.f}, kss[4] = {0.f, 0.f, 0.f, 0.f};

  for (int t2 = 0; t2 < 2; ++t2) {
    const size_t row0 = (size_t)b * Nn + chunk * 256 + t2 * 128;
    const unsigned short* ag = xb + (row0 + sr) * 512 + sko;
    bf16x8 pa[4], pb[4];
#pragma unroll
    for (int p = 0; p < 4; ++p) {
      pa[p] = *(const bf16x8*)(ag + p * 8);
      pb[p] = *(const bf16x8*)(bg + p * 8);
    }
    f32x4 acc[4][4] = {};
    for (int k0 = 0; k0 < 512; k0 += 64) {
      __syncthreads();
#pragma unroll
      for (int p = 0; p < 4; ++p) {
        *(bf16x8*)&As[sr * 72 + sko + p * 8] = pa[p];
        *(bf16x8*)&Bs[sr * 72 + sko + p * 8] = pb[p];
      }
      __syncthreads();
      if (k0 < 448) {
#pragma unroll
        for (int p = 0; p < 4; ++p) {
          pa[p] = *(const bf16x8*)(ag + k0 + 64 + p * 8);
          pb[p] = *(const bf16x8*)(bg + k0 + 64 + p * 8);
        }
      }
#pragma unroll
      for (int ks = 0; ks < 2; ++ks) {
        bf16x8 am[4], bn[4];
#pragma unroll
        for (int q = 0; q < 4; ++q) {
          am[q] = *(const bf16x8*)&As[(64 * wm + 16 * q + i) * 72 + ks * 32 + kq];
          bn[q] = *(const bf16x8*)&Bs[(64 * wn + 16 * q + i) * 72 + ks * 32 + kq];
        }
#pragma unroll
        for (int mi = 0; mi < 4; ++mi)
#pragma unroll
          for (int ni = 0; ni < 4; ++ni)
            acc[mi][ni] = __builtin_amdgcn_mfma_f32_16x16x32_bf16(am[mi], bn[ni], acc[mi][ni], 0, 0, 0);
      }
    }
    __syncthreads();  // As/Bs reads done; safe to overlay kf_t/v_t
    if (wn == 0) {
#pragma unroll
      for (int mi = 0; mi < 4; ++mi) {
        float nrm[4];
#pragma unroll
        for (int r = 0; r < 4; ++r) {
          float s = 0.f;
#pragma unroll
          for (int ni = 0; ni < 4; ++ni) {
            float kx = acc[mi][ni][r] + bias_[ni];
            s += kx * kx;
          }
          nrm[r] = sqrtf(grp16_sum(s));
        }
#pragma unroll
        for (int ni = 0; ni < 4; ++ni)
#pragma unroll
          for (int r = 0; r < 4; ++r) {
            float kx = acc[mi][ni][r] + bias_[ni];
            float dk = tanhf(kx / nrm[r] * 20.0f) * PI4f;
            float a3 = fabsf(kx);
            a3 = a3 * a3 * a3;
            float sn, cs;
            __sincosf(dk, &sn, &cs);
            float kc = a3 * cs, ksn = a3 * sn;
            ksc[ni] += kc;
            kss[ni] += ksn;
            const int nl = 64 * wm + 16 * mi + 4 * g + r;
            kf_t[(16 * ni + i) * 136 + nl] = f2bf(kc);
            kf_t[(64 + 16 * ni + i) * 136 + nl] = f2bf(ksn);
          }
      }
    } else {
#pragma unroll
      for (int mi = 0; mi < 4; ++mi)
#pragma unroll
        for (int ni = 0; ni < 4; ++ni)
#pragma unroll
          for (int r = 0; r < 4; ++r) {
            const int nl = 64 * wm + 16 * mi + 4 * g + r;
            v_t[(16 * ni + i) * 136 + nl] = f2bf(acc[mi][ni][r] + bias_[ni]);
          }
    }
    __syncthreads();
    // kv += kf_t @ v_t^T over this 128-row tile (K = 128 rows)
#pragma unroll
    for (int ks2 = 0; ks2 < 4; ++ks2) {
      bf16x8 a2[4], b2[2];
#pragma unroll
      for (int mi = 0; mi < 4; ++mi)
        a2[mi] = *(const bf16x8*)&kf_t[(64 * wm + 16 * mi + i) * 136 + ks2 * 32 + kq];
#pragma unroll
      for (int ni = 0; ni < 2; ++ni)
        b2[ni] = *(const bf16x8*)&v_t[(32 * wn + 16 * ni + i) * 136 + ks2 * 32 + kq];
#pragma unroll
      for (int mi = 0; mi < 4; ++mi)
#pragma unroll
        for (int ni = 0; ni < 2; ++ni)
          kvf[mi][ni] = __builtin_amdgcn_mfma_f32_16x16x32_bf16(a2[mi], b2[ni], kvf[mi][ni], 0, 0, 0);
    }
  }
  float* pw = part + (size_t)blockIdx.x * PART;
#pragma unroll
  for (int mi = 0; mi < 4; ++mi)
#pragma unroll
    for (int ni = 0; ni < 2; ++ni)
#pragma unroll
      for (int r = 0; r < 4; ++r)
        pw[(64 * wm + 16 * mi + 4 * g + r) * 64 + 32 * wn + 16 * ni + i] = kvf[mi][ni][r];
  if (wn == 0) {
#pragma unroll
    for (int ni = 0; ni < 4; ++ni) {
      float c = ksc[ni];
      c += __shfl_xor(c, 16);
      c += __shfl_xor(c, 32);
      float s = kss[ni];
      s += __shfl_xor(s, 16);
      s += __shfl_xor(s, 32);
      if (lane < 16) {
        ksl[wm * 128 + 16 * ni + lane] = c;
        ksl[wm * 128 + 64 + 16 * ni + lane] = s;
      }
    }
  }
  __syncthreads();
  if (t < 128) pw[8192 + t] = ksl[t] + ksl[128 + t];
}

// ============ K1b: reduce partials -> kv^T bf16 [bh][d][f] and k_mean fp32 ============
__global__ __launch_bounds__(256) void kv_reduce(const float* __restrict__ part,
                                                 unsigned short* __restrict__ kvt,
                                                 float* __restrict__ kmean) {
  const int bh = blockIdx.x;
  const float invN = 1.0f / Nn;
  const size_t base = (size_t)bh * CHB * PART;
  for (int idx = threadIdx.x; idx < 8192; idx += 256) {
    float s = 0.f;
#pragma unroll
    for (int c = 0; c < CHB; ++c) s += part[base + (size_t)c * PART + idx];
    int f = idx >> 6, d = idx & 63;
    kvt[(size_t)bh * 8192 + d * 128 + f] = f2bf(s * invN);
  }
  if (threadIdx.x < 128) {
    float s = 0.f;
#pragma unroll
    for (int c = 0; c < CHB; ++c) s += part[base + (size_t)c * PART + 8192 + threadIdx.x];
    kmean[bh * 128 + threadIdx.x] = s * invN;
  }
}

// ============ K2: fused Q-GEMM (LDS-staged MFMA) + qf/z + PV (MFMA) -> att bf16 ============
// grid 2048: bh = bid>>5, chunk = bid&31 (128 rows)
__global__ __launch_bounds__(256) void attn_kernel(const unsigned short* __restrict__ xb,
                                                   const unsigned short* __restrict__ wt,
                                                   const float* __restrict__ qkvb,
                                                   const unsigned short* __restrict__ kvt,
                                                   const float* __restrict__ kmean,
                                                   unsigned short* __restrict__ attb) {
  __shared__ char smraw[52736];
  unsigned short* As = (unsigned short*)smraw;               // [128][72] (GEMM)
  unsigned short* Bs = As + 128 * 72;                        // [64][72]
  unsigned short* qf_t = (unsigned short*)smraw;             // [128][136] (overlays As/Bs)
  unsigned short* kv_s = (unsigned short*)(smraw + 34816);   // [64][136]
  float* km = (float*)(smraw + 34816 + 17408);               // [128]
  const int t = threadIdx.x, lane = t & 63, wv = t >> 6;
  const int i = lane & 15, g = lane >> 4, kq = g * 8;
  const int bh = blockIdx.x >> 5, chunk = blockIdx.x & 31;
  const int b = bh >> 3, h = bh & 7;
  const size_t row0 = (size_t)b * Nn + chunk * 128;
  if (t < 128) km[t] = kmean[bh * 128 + t];
  {
    const unsigned short* src = kvt + (size_t)bh * 8192;
#pragma unroll
    for (int it = 0; it < 4; ++it) {
      int idx = t + it * 256;
      int d = idx >> 4, f8 = (idx & 15) * 8;
      *(bf16x8*)&kv_s[d * 136 + f8] = *(const bf16x8*)(src + d * 128 + f8);
    }
  }
  const int sr = t >> 1, sko = (t & 1) * 32;
  const int c2 = t >> 2, ko2 = (t & 3) * 16;
  const unsigned short* ag = xb + (row0 + sr) * 512 + sko;
  const unsigned short* bgq = wt + (size_t)(h * 64 + c2) * 512 + ko2;
  bf16x8 pa[4], pb[2];
#pragma unroll
  for (int p = 0; p < 4; ++p) pa[p] = *(const bf16x8*)(ag + p * 8);
#pragma unroll
  for (int p = 0; p < 2; ++p) pb[p] = *(const bf16x8*)(bgq + p * 8);
  f32x4 acc[2][4] = {};
  for (int k0 = 0; k0 < 512; k0 += 64) {
    __syncthreads();
#pragma unroll
    for (int p = 0; p < 4; ++p) *(bf16x8*)&As[sr * 72 + sko + p * 8] = pa[p];
#pragma unroll
    for (int p = 0; p < 2; ++p) *(bf16x8*)&Bs[c2 * 72 + ko2 + p * 8] = pb[p];
    __syncthreads();
    if (k0 < 448) {
#pragma unroll
      for (int p = 0; p < 4; ++p) pa[p] = *(const bf16x8*)(ag + k0 + 64 + p * 8);
#pragma unroll
      for (int p = 0; p < 2; ++p) pb[p] = *(const bf16x8*)(bgq + k0 + 64 + p * 8);
    }
#pragma unroll
    for (int ks = 0; ks < 2; ++ks) {
      bf16x8 am[2], bn[4];
#pragma unroll
      for (int mi = 0; mi < 2; ++mi)
        am[mi] = *(const bf16x8*)&As[(32 * wv + 16 * mi + i) * 72 + ks * 32 + kq];
#pragma unroll
      for (int ni = 0; ni < 4; ++ni)
        bn[ni] = *(const bf16x8*)&Bs[(16 * ni + i) * 72 + ks * 32 + kq];
#pragma unroll
      for (int mi = 0; mi < 2; ++mi)
#pragma unroll
        for (int ni = 0; ni < 4; ++ni)
          acc[mi][ni] = __builtin_amdgcn_mfma_f32_16x16x32_bf16(am[mi], bn[ni], acc[mi][ni], 0, 0, 0);
    }
  }
  __syncthreads();  // As/Bs dead; overlay qf_t
  float bqv[4];
#pragma unroll
  for (int ni = 0; ni < 4; ++ni) bqv[ni] = qkvb[h * 64 + 16 * ni + i];
  float z[2][4];
#pragma unroll
  for (int mi = 0; mi < 2; ++mi) {
    float nrm[4];
#pragma unroll
    for (int r = 0; r < 4; ++r) {
      float s = 0.f;
#pragma unroll
      for (int ni = 0; ni < 4; ++ni) {
        float q = acc[mi][ni][r] + bqv[ni];
        s += q * q;
      }
      nrm[r] = sqrtf(grp16_sum(s));
    }
#pragma unroll
    for (int r = 0; r < 4; ++r) {
      float pwr = 1.5f * (0.5f + tanhf(nrm[r]));
      float dp = 0.f;
      const int nl = 32 * wv + 16 * mi + 4 * g + r;
#pragma unroll
      for (int ni = 0; ni < 4; ++ni) {
        float q = acc[mi][ni][r] + bqv[ni];
        float qt = q / nrm[r];
        float dq = tanhf(qt * 20.0f) * PI4f;
        float qtp = exp2f(pwr * __log2f(qt * qt));
        float sn, cs;
        __sincosf(dq, &sn, &cs);
        float qc = qtp * cs, qs = qtp * sn;
        dp += qc * km[16 * ni + i] + qs * km[64 + 16 * ni + i];
        qf_t[nl * 136 + 16 * ni + i] = f2bf(qc);
        qf_t[nl * 136 + 64 + 16 * ni + i] = f2bf(qs);
      }
      z[mi][r] = 1.0f / (grp16_sum(dp) + 1e-6f);
    }
  }
  __syncthreads();
  f32x4 pacc[2][4] = {};
#pragma unroll
  for (int ks2 = 0; ks2 < 4; ++ks2) {
    bf16x8 a2[2], b2[4];
#pragma unroll
    for (int mi = 0; mi < 2; ++mi)
      a2[mi] = *(const bf16x8*)&qf_t[(32 * wv + 16 * mi + i) * 136 + ks2 * 32 + kq];
#pragma unroll
    for (int ni = 0; ni < 4; ++ni)
      b2[ni] = *(const bf16x8*)&kv_s[(16 * ni + i) * 136 + ks2 * 32 + kq];
#pragma unroll
    for (int mi = 0; mi < 2; ++mi)
#pragma unroll
      for (int ni = 0; ni < 4; ++ni)
        pacc[mi][ni] = __builtin_amdgcn_mfma_f32_16x16x32_bf16(a2[mi], b2[ni], pacc[mi][ni], 0, 0, 0);
  }
#pragma unroll
  for (int mi = 0; mi < 2; ++mi)
#pragma unroll
    for (int ni = 0; ni < 4; ++ni)
#pragma unroll
      for (int r = 0; r < 4; ++r)
        attb[(row0 + 32 * wv + 16 * mi + 4 * g + r) * 512 + h * 64 + 16 * ni + i] =
            f2bf(pacc[mi][ni][r] * z[mi][r]);
}

// ============ in-place LayerNorm on bf16 att ============
__global__ __launch_bounds__(256) void ln_kernel(unsigned short* __restrict__ attb,
                                                 const float* __restrict__ gg,
                                                 const float* __restrict__ bb) {
  const int lane = threadIdx.x & 63, wv = threadIdx.x >> 6;
  const size_t row = (size_t)blockIdx.x * 4 + wv;
  unsigned short* p = attb + row * 512 + lane * 8;
  bf16x8 v = *(bf16x8*)p;
  float x[8];
#pragma unroll
  for (int j = 0; j < 8; ++j) x[j] = bf2f((unsigned short)v[j]);
  float s = 0.f;
#pragma unroll
  for (int j = 0; j < 8; ++j) s += x[j];
  const float mu = wsum64(s) * (1.0f / 512.0f);
  float sq = 0.f;
#pragma unroll
  for (int j = 0; j < 8; ++j) {
    float d = x[j] - mu;
    sq += d * d;
  }
  const float rstd = rsqrtf(wsum64(sq) * (1.0f / 512.0f) + 1e-5f);
  const float4 g0 = *(const float4*)(gg + lane * 8);
  const float4 g1 = *(const float4*)(gg + lane * 8 + 4);
  const float4 b0 = *(const float4*)(bb + lane * 8);
  const float4 b1 = *(const float4*)(bb + lane * 8 + 4);
  float gv[8] = {g0.x, g0.y, g0.z, g0.w, g1.x, g1.y, g1.z, g1.w};
  float bv[8] = {b0.x, b0.y, b0.z, b0.w, b1.x, b1.y, b1.z, b1.w};
#pragma unroll
  for (int j = 0; j < 8; ++j)
    v[j] = (short)f2bf((x[j] - mu) * rstd * gv[j] + bv[j]);
  *(bf16x8*)p = v;
}

// ============ K3: final GEMM (bf16 MFMA): out = ln_att @ out_w + bias ============
__global__ __launch_bounds__(256) void out_gemm(const unsigned short* __restrict__ attb,
                                                const unsigned short* __restrict__ owt,
                                                const float* __restrict__ ob,
                                                float* __restrict__ outp) {
  __shared__ unsigned short As[128 * 72];
  __shared__ unsigned short Bs[128 * 72];
  const int t = threadIdx.x, lane = t & 63, wv = t >> 6;
  const int i = lane & 15, g = lane >> 4, kq = g * 8;
  const int wm = wv >> 1, wn = wv & 1;
  const int m0 = (blockIdx.x >> 2) * 128, n0 = (blockIdx.x & 3) * 128;
  const int sr = t >> 1, sko = (t & 1) * 32;
  const unsigned short* ag = attb + (size_t)(m0 + sr) * 512 + sko;
  const unsigned short* bg = owt + (size_t)(n0 + sr) * 512 + sko;
  f32x4 acc[4][4] = {};
  bf16x8 pa[4], pb[4];
#pragma unroll
  for (int p = 0; p < 4; ++p) {
    pa[p] = *(const bf16x8*)(ag + p * 8);
    pb[p] = *(const bf16x8*)(bg + p * 8);
  }
  for (int k0 = 0; k0 < 512; k0 += 64) {
    __syncthreads();
#pragma unroll
    for (int p = 0; p < 4; ++p) {
      *(bf16x8*)&As[sr * 72 + sko + p * 8] = pa[p];
      *(bf16x8*)&Bs[sr * 72 + sko + p * 8] = pb[p];
    }
    __syncthreads();
    if (k0 < 448) {
#pragma unroll
      for (int p = 0; p < 4; ++p) {
        pa[p] = *(const bf16x8*)(ag + k0 + 64 + p * 8);
        pb[p] = *(const bf16x8*)(bg + k0 + 64 + p * 8);
      }
    }
#pragma unroll
    for (int ks = 0; ks < 2; ++ks) {
      bf16x8 am[4], bn[4];
#pragma unroll
      for (int q = 0; q < 4; ++q) {
        am[q] = *(const bf16x8*)&As[(64 * wm + 16 * q + i) * 72 + ks * 32 + kq];
        bn[q] = *(const bf16x8*)&Bs[(64 * wn + 16 * q + i) * 72 + ks * 32 + kq];
      }
#pragma unroll
      for (int mi = 0; mi < 4; ++mi)
#pragma unroll
        for (int ni = 0; ni < 4; ++ni)
          acc[mi][ni] = __builtin_amdgcn_mfma_f32_16x16x32_bf16(am[mi], bn[ni], acc[mi][ni], 0, 0, 0);
    }
  }
#pragma unroll
  for (int ni = 0; ni < 4; ++ni) {
    float bv = ob[n0 + 64 * wn + 16 * ni + i];
#pragma unroll
    for (int mi = 0; mi < 4; ++mi)
#pragma unroll
      for (int r = 0; r < 4; ++r)
        outp[(size_t)(m0 + 64 * wm + 16 * mi + 4 * g + r) * 512 + n0 + 64 * wn +
             16 * ni + i] = acc[mi][ni][r] + bv;
  }
}

extern "C" void kernel_launch(void* const* d_in, const int* in_sizes, int n_in,
                              void* d_out, int out_size, void* d_ws,
                              size_t ws_size, hipStream_t stream) {
  const float* x = (const float*)d_in[0];
  const float* qkv_w = (const float*)d_in[1];
  const float* qkv_b = (const float*)d_in[2];
  const float* ln_g = (const float*)d_in[3];
  const float* ln_b = (const float*)d_in[4];
  const float* out_w = (const float*)d_in[5];
  const float* out_b = (const float*)d_in[6];
  float* out = (float*)d_out;

  char* w = (char*)d_ws;
  unsigned short* xb = (unsigned short*)w;                    // 33,554,432 B
  unsigned short* wt = (unsigned short*)(w + 33554432);       // 1,572,864 B
  unsigned short* owt = (unsigned short*)(w + 35127296);      // 524,288 B
  unsigned short* kvt = (unsigned short*)(w + 35651584);      // 1,048,576 B
  float* kmean = (float*)(w + 36700160);                      // 32,768 B
  char* R = w + 36732928;
  float* part = (float*)R;                    // 1024*8320*4 = 34,078,720 B
  unsigned short* attb = (unsigned short*)R;  // 33,554,432 B (aliases part; part dead by then)

  x_convert<<<8192, 256, 0, stream>>>(x, xb);
  w_transpose<<<256, 256, 0, stream>>>(qkv_w, out_w, wt, owt);
  kv_kernel<<<1024, 256, 0, stream>>>(xb, wt, qkv_b, part);
  kv_reduce<<<64, 256, 0, stream>>>(part, kvt, kmean);
  attn_kernel<<<2048, 256, 0, stream>>>(xb, wt, qkv_b, kvt, kmean, attb);
  ln_kernel<<<8192, 256, 0, stream>>>(attb, ln_g, ln_b);
  out_gemm<<<1024, 256, 0, stream>>>(attb, owt, out_b, out);
}

// Round 5
// 357.816 us; speedup vs baseline: 4.2419x; 1.1166x over previous
//
#include <hip/hip_runtime.h>
#include <math.h>

#define Bb 8
#define Nn 4096
#define Cc 512
#define Hh 8
#define Dd 64
#define Ff 128
#define M_ROWS (Bb * Nn)
#define PI4f 0.78539816339744830962f
#define CHB 16
#define PART 8320  // 128*64 kv + 128 ksum

using bf16x8 = __attribute__((ext_vector_type(8))) short;
using f32x4 = __attribute__((ext_vector_type(4))) float;

__device__ __forceinline__ unsigned short f2bf(float f) {
  unsigned u = __float_as_uint(f);
  u += 0x7FFFu + ((u >> 16) & 1u);
  return (unsigned short)(u >> 16);
}
__device__ __forceinline__ float bf2f(unsigned short h) {
  return __uint_as_float(((unsigned)h) << 16);
}
__device__ __forceinline__ float grp16_sum(float v) {
  v += __shfl_xor(v, 1);
  v += __shfl_xor(v, 2);
  v += __shfl_xor(v, 4);
  v += __shfl_xor(v, 8);
  return v;
}
__device__ __forceinline__ float wsum64(float v) {
#pragma unroll
  for (int m = 32; m >= 1; m >>= 1) v += __shfl_xor(v, m, 64);
  return v;
}
// tanh(x) = 1 - 2/(e^{2x}+1); exact at +-inf, ~1e-7 rel error, ~6 VALU ops
__device__ __forceinline__ float fast_tanh(float x) {
  float e = __expf(2.0f * x);
  return 1.0f - 2.0f / (e + 1.0f);
}

// ============ convert x (fp32 -> bf16), 8192 blocks ============
__global__ __launch_bounds__(256) void x_convert(const float* __restrict__ x,
                                                 unsigned short* __restrict__ xb) {
  size_t i = ((size_t)blockIdx.x * 256 + threadIdx.x) * 8;
  float4 a = *(const float4*)(x + i);
  float4 b = *(const float4*)(x + i + 4);
  int4 o;
  o.x = (int)f2bf(a.x) | ((int)f2bf(a.y) << 16);
  o.y = (int)f2bf(a.z) | ((int)f2bf(a.w) << 16);
  o.z = (int)f2bf(b.x) | ((int)f2bf(b.y) << 16);
  o.w = (int)f2bf(b.z) | ((int)f2bf(b.w) << 16);
  *(int4*)(xb + i) = o;
}

// ============ transpose qkv_w (512x1536) and out_w (512x512) -> bf16 [col][k] ============
__global__ __launch_bounds__(256) void w_transpose(const float* __restrict__ qkvw,
                                                   const float* __restrict__ outw,
                                                   unsigned short* __restrict__ wt,
                                                   unsigned short* __restrict__ owt) {
  __shared__ float tile[64][65];
  const int bid = blockIdx.x;
  const float* src;
  unsigned short* dst;
  int ldsrc, j0, k0;
  if (bid < 192) {
    src = qkvw; dst = wt; ldsrc = 1536;
    j0 = (bid % 24) * 64; k0 = (bid / 24) * 64;
  } else {
    int r = bid - 192;
    src = outw; dst = owt; ldsrc = 512;
    j0 = (r & 7) * 64; k0 = (r >> 3) * 64;
  }
  const int t = threadIdx.x;
  const int rr = t >> 4, cc = (t & 15) * 4;
#pragma unroll
  for (int it = 0; it < 4; ++it) {
    float4 v = *(const float4*)(src + (size_t)(k0 + rr + it * 16) * ldsrc + j0 + cc);
    tile[rr + it * 16][cc + 0] = v.x;
    tile[rr + it * 16][cc + 1] = v.y;
    tile[rr + it * 16][cc + 2] = v.z;
    tile[rr + it * 16][cc + 3] = v.w;
  }
  __syncthreads();
  const int j = t >> 2, kq = (t & 3) * 16;
  unsigned short u[16];
#pragma unroll
  for (int p = 0; p < 16; ++p) u[p] = f2bf(tile[kq + p][j]);
  int4 o;
  o.x = (int)u[0] | ((int)u[1] << 16);
  o.y = (int)u[2] | ((int)u[3] << 16);
  o.z = (int)u[4] | ((int)u[5] << 16);
  o.w = (int)u[6] | ((int)u[7] << 16);
  int4 o2;
  o2.x = (int)u[8] | ((int)u[9] << 16);
  o2.y = (int)u[10] | ((int)u[11] << 16);
  o2.z = (int)u[12] | ((int)u[13] << 16);
  o2.w = (int)u[14] | ((int)u[15] << 16);
  *(int4*)(dst + (size_t)(j0 + j) * 512 + k0 + kq) = o;
  *(int4*)(dst + (size_t)(j0 + j) * 512 + k0 + kq + 8) = o2;
}

// ============ K1: fused KV-GEMM (LDS-staged MFMA) + feature map + kv/ksum partials ============
// grid 1024: bh = bid>>4, chunk = bid&15 (256 rows = 2 tiles of 128)
// Waves own 32-row strips x all 128 cols => feature map balanced over all 4 waves.
__global__ __launch_bounds__(256) void kv_kernel(const unsigned short* __restrict__ xb,
                                                 const unsigned short* __restrict__ wt,
                                                 const float* __restrict__ qkvb,
                                                 float* __restrict__ part) {
  __shared__ char smraw[54272];
  unsigned short* As = (unsigned short*)smraw;              // [128][72] (GEMM phase)
  unsigned short* Bs = As + 128 * 72;                       // [128][72]
  unsigned short* kf_t = (unsigned short*)smraw;            // [128][136] (epilogue overlay)
  unsigned short* v_t = kf_t + 128 * 136;                   // [64][136]
  float* ksl = (float*)(smraw + 52224);                     // [4][128]
  const int t = threadIdx.x, lane = t & 63, wv = t >> 6;
  const int i = lane & 15, g = lane >> 4, kq = g * 8;
  const int bh = blockIdx.x >> 4, chunk = blockIdx.x & 15;
  const int b = bh >> 3, h = bh & 7;
  const int sr = t >> 1, sko = (t & 1) * 32;
  const int wrow = (sr < 64) ? (512 + h * 64 + sr) : (1024 + h * 64 + sr - 64);
  const unsigned short* bg = wt + (size_t)wrow * 512 + sko;
  float bias_[8];
#pragma unroll
  for (int ni = 0; ni < 4; ++ni) bias_[ni] = qkvb[512 + h * 64 + 16 * ni + i];
#pragma unroll
  for (int ni = 4; ni < 8; ++ni) bias_[ni] = qkvb[1024 + h * 64 + 16 * (ni - 4) + i];
  f32x4 kvf[2][4] = {};
  float ksc[4] = {0.f, 0.f, 0.f, 0.f}, kss[4] = {0.f, 0.f, 0.f, 0.f};
  const size_t rowbase = (size_t)b * Nn + chunk * 256;
  const unsigned short* ag0 = xb + (rowbase + sr) * 512 + sko;
  bf16x8 pa[4], pb[4];
#pragma unroll
  for (int p = 0; p < 4; ++p) {
    pa[p] = *(const bf16x8*)(ag0 + p * 8);
    pb[p] = *(const bf16x8*)(bg + p * 8);
  }
  for (int t2 = 0; t2 < 2; ++t2) {
    const unsigned short* ag = xb + (rowbase + t2 * 128 + sr) * 512 + sko;
    f32x4 acc[2][8] = {};
    for (int k0 = 0; k0 < 512; k0 += 64) {
      __syncthreads();
#pragma unroll
      for (int p = 0; p < 4; ++p) {
        *(bf16x8*)&As[sr * 72 + sko + p * 8] = pa[p];
        *(bf16x8*)&Bs[sr * 72 + sko + p * 8] = pb[p];
      }
      __syncthreads();
      if (k0 < 448) {
#pragma unroll
        for (int p = 0; p < 4; ++p) {
          pa[p] = *(const bf16x8*)(ag + k0 + 64 + p * 8);
          pb[p] = *(const bf16x8*)(bg + k0 + 64 + p * 8);
        }
      } else if (t2 == 0) {
        // prefetch next tile's first K-chunk; latency hides under epilogue
        const unsigned short* ag1 = ag + 128 * 512;
#pragma unroll
        for (int p = 0; p < 4; ++p) {
          pa[p] = *(const bf16x8*)(ag1 + p * 8);
          pb[p] = *(const bf16x8*)(bg + p * 8);
        }
      }
#pragma unroll
      for (int ks = 0; ks < 2; ++ks) {
        bf16x8 am[2], bn[8];
#pragma unroll
        for (int mi = 0; mi < 2; ++mi)
          am[mi] = *(const bf16x8*)&As[(32 * wv + 16 * mi + i) * 72 + ks * 32 + kq];
#pragma unroll
        for (int ni = 0; ni < 8; ++ni)
          bn[ni] = *(const bf16x8*)&Bs[(16 * ni + i) * 72 + ks * 32 + kq];
#pragma unroll
        for (int mi = 0; mi < 2; ++mi)
#pragma unroll
          for (int ni = 0; ni < 8; ++ni)
            acc[mi][ni] = __builtin_amdgcn_mfma_f32_16x16x32_bf16(am[mi], bn[ni], acc[mi][ni], 0, 0, 0);
      }
    }
    __syncthreads();  // As/Bs reads done; safe to overlay kf_t/v_t
    // feature map: each wave handles its own 32 rows (all 4 waves busy)
#pragma unroll
    for (int mi = 0; mi < 2; ++mi) {
      float nrm[4];
#pragma unroll
      for (int r = 0; r < 4; ++r) {
        float s = 0.f;
#pragma unroll
        for (int ni = 0; ni < 4; ++ni) {
          float kx = acc[mi][ni][r] + bias_[ni];
          s += kx * kx;
        }
        nrm[r] = sqrtf(grp16_sum(s));
      }
#pragma unroll
      for (int ni = 0; ni < 4; ++ni)
#pragma unroll
        for (int r = 0; r < 4; ++r) {
          float kx = acc[mi][ni][r] + bias_[ni];
          float dk = fast_tanh(kx / nrm[r] * 20.0f) * PI4f;
          float a3 = fabsf(kx);
          a3 = a3 * a3 * a3;
          float sn, cs;
          __sincosf(dk, &sn, &cs);
          float kc = a3 * cs, ksn = a3 * sn;
          ksc[ni] += kc;
          kss[ni] += ksn;
          const int nl = 32 * wv + 16 * mi + 4 * g + r;
          kf_t[(16 * ni + i) * 136 + nl] = f2bf(kc);
          kf_t[(64 + 16 * ni + i) * 136 + nl] = f2bf(ksn);
        }
#pragma unroll
      for (int ni = 4; ni < 8; ++ni)
#pragma unroll
        for (int r = 0; r < 4; ++r) {
          const int nl = 32 * wv + 16 * mi + 4 * g + r;
          v_t[(16 * (ni - 4) + i) * 136 + nl] = f2bf(acc[mi][ni][r] + bias_[ni]);
        }
    }
    __syncthreads();
    // kv += kf_t @ v_t^T over this 128-row tile; wave owns f-strip 32*wv
#pragma unroll
    for (int ks2 = 0; ks2 < 4; ++ks2) {
      bf16x8 a2[2], b2[4];
#pragma unroll
      for (int mi = 0; mi < 2; ++mi)
        a2[mi] = *(const bf16x8*)&kf_t[(32 * wv + 16 * mi + i) * 136 + ks2 * 32 + kq];
#pragma unroll
      for (int ni = 0; ni < 4; ++ni)
        b2[ni] = *(const bf16x8*)&v_t[(16 * ni + i) * 136 + ks2 * 32 + kq];
#pragma unroll
      for (int mi = 0; mi < 2; ++mi)
#pragma unroll
        for (int ni = 0; ni < 4; ++ni)
          kvf[mi][ni] = __builtin_amdgcn_mfma_f32_16x16x32_bf16(a2[mi], b2[ni], kvf[mi][ni], 0, 0, 0);
    }
  }
  float* pw = part + (size_t)blockIdx.x * PART;
#pragma unroll
  for (int mi = 0; mi < 2; ++mi)
#pragma unroll
    for (int ni = 0; ni < 4; ++ni)
#pragma unroll
      for (int r = 0; r < 4; ++r)
        pw[(32 * wv + 16 * mi + 4 * g + r) * 64 + 16 * ni + i] = kvf[mi][ni][r];
  // ksum partials: reduce over g-groups, then over waves via LDS
#pragma unroll
  for (int ni = 0; ni < 4; ++ni) {
    float c = ksc[ni];
    c += __shfl_xor(c, 16);
    c += __shfl_xor(c, 32);
    float s = kss[ni];
    s += __shfl_xor(s, 16);
    s += __shfl_xor(s, 32);
    if (lane < 16) {
      ksl[wv * 128 + 16 * ni + lane] = c;
      ksl[wv * 128 + 64 + 16 * ni + lane] = s;
    }
  }
  __syncthreads();
  if (t < 128) pw[8192 + t] = ksl[t] + ksl[128 + t] + ksl[256 + t] + ksl[384 + t];
}

// ============ K1b: reduce partials -> kv^T bf16 [bh][d][f] and k_mean fp32 ============
__global__ __launch_bounds__(256) void kv_reduce(const float* __restrict__ part,
                                                 unsigned short* __restrict__ kvt,
                                                 float* __restrict__ kmean) {
  const int bh = blockIdx.x;
  const float invN = 1.0f / Nn;
  const size_t base = (size_t)bh * CHB * PART;
  for (int idx = threadIdx.x; idx < 8192; idx += 256) {
    float s = 0.f;
#pragma unroll
    for (int c = 0; c < CHB; ++c) s += part[base + (size_t)c * PART + idx];
    int f = idx >> 6, d = idx & 63;
    kvt[(size_t)bh * 8192 + d * 128 + f] = f2bf(s * invN);
  }
  if (threadIdx.x < 128) {
    float s = 0.f;
#pragma unroll
    for (int c = 0; c < CHB; ++c) s += part[base + (size_t)c * PART + 8192 + threadIdx.x];
    kmean[bh * 128 + threadIdx.x] = s * invN;
  }
}

// ============ K2: fused Q-GEMM (LDS-staged MFMA) + qf/z + PV (MFMA) -> att bf16 ============
// grid 2048: bh = bid>>5, chunk = bid&31 (128 rows)
__global__ __launch_bounds__(256) void attn_kernel(const unsigned short* __restrict__ xb,
                                                   const unsigned short* __restrict__ wt,
                                                   const float* __restrict__ qkvb,
                                                   const unsigned short* __restrict__ kvt,
                                                   const float* __restrict__ kmean,
                                                   unsigned short* __restrict__ attb) {
  __shared__ char smraw[52736];
  unsigned short* As = (unsigned short*)smraw;               // [128][72] (GEMM)
  unsigned short* Bs = As + 128 * 72;                        // [64][72]
  unsigned short* qf_t = (unsigned short*)smraw;             // [128][136] (overlays As/Bs)
  unsigned short* kv_s = (unsigned short*)(smraw + 34816);   // [64][136]
  float* km = (float*)(smraw + 34816 + 17408);               // [128]
  const int t = threadIdx.x, lane = t & 63, wv = t >> 6;
  const int i = lane & 15, g = lane >> 4, kq = g * 8;
  const int bh = blockIdx.x >> 5, chunk = blockIdx.x & 31;
  const int b = bh >> 3, h = bh & 7;
  const size_t row0 = (size_t)b * Nn + chunk * 128;
  if (t < 128) km[t] = kmean[bh * 128 + t];
  {
    const unsigned short* src = kvt + (size_t)bh * 8192;
#pragma unroll
    for (int it = 0; it < 4; ++it) {
      int idx = t + it * 256;
      int d = idx >> 4, f8 = (idx & 15) * 8;
      *(bf16x8*)&kv_s[d * 136 + f8] = *(const bf16x8*)(src + d * 128 + f8);
    }
  }
  const int sr = t >> 1, sko = (t & 1) * 32;
  const int c2 = t >> 2, ko2 = (t & 3) * 16;
  const unsigned short* ag = xb + (row0 + sr) * 512 + sko;
  const unsigned short* bgq = wt + (size_t)(h * 64 + c2) * 512 + ko2;
  bf16x8 pa[4], pb[2];
#pragma unroll
  for (int p = 0; p < 4; ++p) pa[p] = *(const bf16x8*)(ag + p * 8);
#pragma unroll
  for (int p = 0; p < 2; ++p) pb[p] = *(const bf16x8*)(bgq + p * 8);
  f32x4 acc[2][4] = {};
  for (int k0 = 0; k0 < 512; k0 += 64) {
    __syncthreads();
#pragma unroll
    for (int p = 0; p < 4; ++p) *(bf16x8*)&As[sr * 72 + sko + p * 8] = pa[p];
#pragma unroll
    for (int p = 0; p < 2; ++p) *(bf16x8*)&Bs[c2 * 72 + ko2 + p * 8] = pb[p];
    __syncthreads();
    if (k0 < 448) {
#pragma unroll
      for (int p = 0; p < 4; ++p) pa[p] = *(const bf16x8*)(ag + k0 + 64 + p * 8);
#pragma unroll
      for (int p = 0; p < 2; ++p) pb[p] = *(const bf16x8*)(bgq + k0 + 64 + p * 8);
    }
#pragma unroll
    for (int ks = 0; ks < 2; ++ks) {
      bf16x8 am[2], bn[4];
#pragma unroll
      for (int mi = 0; mi < 2; ++mi)
        am[mi] = *(const bf16x8*)&As[(32 * wv + 16 * mi + i) * 72 + ks * 32 + kq];
#pragma unroll
      for (int ni = 0; ni < 4; ++ni)
        bn[ni] = *(const bf16x8*)&Bs[(16 * ni + i) * 72 + ks * 32 + kq];
#pragma unroll
      for (int mi = 0; mi < 2; ++mi)
#pragma unroll
        for (int ni = 0; ni < 4; ++ni)
          acc[mi][ni] = __builtin_amdgcn_mfma_f32_16x16x32_bf16(am[mi], bn[ni], acc[mi][ni], 0, 0, 0);
    }
  }
  __syncthreads();  // As/Bs dead; overlay qf_t
  float bqv[4];
#pragma unroll
  for (int ni = 0; ni < 4; ++ni) bqv[ni] = qkvb[h * 64 + 16 * ni + i];
  float z[2][4];
#pragma unroll
  for (int mi = 0; mi < 2; ++mi) {
    float nrm[4];
#pragma unroll
    for (int r = 0; r < 4; ++r) {
      float s = 0.f;
#pragma unroll
      for (int ni = 0; ni < 4; ++ni) {
        float q = acc[mi][ni][r] + bqv[ni];
        s += q * q;
      }
      nrm[r] = sqrtf(grp16_sum(s));
    }
#pragma unroll
    for (int r = 0; r < 4; ++r) {
      float pwr = 1.5f * (0.5f + fast_tanh(nrm[r]));
      float dp = 0.f;
      const int nl = 32 * wv + 16 * mi + 4 * g + r;
#pragma unroll
      for (int ni = 0; ni < 4; ++ni) {
        float q = acc[mi][ni][r] + bqv[ni];
        float qt = q / nrm[r];
        float dq = fast_tanh(qt * 20.0f) * PI4f;
        float qtp = exp2f(pwr * __log2f(qt * qt));
        float sn, cs;
        __sincosf(dq, &sn, &cs);
        float qc = qtp * cs, qs = qtp * sn;
        dp += qc * km[16 * ni + i] + qs * km[64 + 16 * ni + i];
        qf_t[nl * 136 + 16 * ni + i] = f2bf(qc);
        qf_t[nl * 136 + 64 + 16 * ni + i] = f2bf(qs);
      }
      z[mi][r] = 1.0f / (grp16_sum(dp) + 1e-6f);
    }
  }
  __syncthreads();
  f32x4 pacc[2][4] = {};
#pragma unroll
  for (int ks2 = 0; ks2 < 4; ++ks2) {
    bf16x8 a2[2], b2[4];
#pragma unroll
    for (int mi = 0; mi < 2; ++mi)
      a2[mi] = *(const bf16x8*)&qf_t[(32 * wv + 16 * mi + i) * 136 + ks2 * 32 + kq];
#pragma unroll
    for (int ni = 0; ni < 4; ++ni)
      b2[ni] = *(const bf16x8*)&kv_s[(16 * ni + i) * 136 + ks2 * 32 + kq];
#pragma unroll
    for (int mi = 0; mi < 2; ++mi)
#pragma unroll
      for (int ni = 0; ni < 4; ++ni)
        pacc[mi][ni] = __builtin_amdgcn_mfma_f32_16x16x32_bf16(a2[mi], b2[ni], pacc[mi][ni], 0, 0, 0);
  }
#pragma unroll
  for (int mi = 0; mi < 2; ++mi)
#pragma unroll
    for (int ni = 0; ni < 4; ++ni)
#pragma unroll
      for (int r = 0; r < 4; ++r)
        attb[(row0 + 32 * wv + 16 * mi + 4 * g + r) * 512 + h * 64 + 16 * ni + i] =
            f2bf(pacc[mi][ni][r] * z[mi][r]);
}

// ============ in-place LayerNorm on bf16 att ============
__global__ __launch_bounds__(256) void ln_kernel(unsigned short* __restrict__ attb,
                                                 const float* __restrict__ gg,
                                                 const float* __restrict__ bb) {
  const int lane = threadIdx.x & 63, wv = threadIdx.x >> 6;
  const size_t row = (size_t)blockIdx.x * 4 + wv;
  unsigned short* p = attb + row * 512 + lane * 8;
  bf16x8 v = *(bf16x8*)p;
  float x[8];
#pragma unroll
  for (int j = 0; j < 8; ++j) x[j] = bf2f((unsigned short)v[j]);
  float s = 0.f;
#pragma unroll
  for (int j = 0; j < 8; ++j) s += x[j];
  const float mu = wsum64(s) * (1.0f / 512.0f);
  float sq = 0.f;
#pragma unroll
  for (int j = 0; j < 8; ++j) {
    float d = x[j] - mu;
    sq += d * d;
  }
  const float rstd = rsqrtf(wsum64(sq) * (1.0f / 512.0f) + 1e-5f);
  const float4 g0 = *(const float4*)(gg + lane * 8);
  const float4 g1 = *(const float4*)(gg + lane * 8 + 4);
  const float4 b0 = *(const float4*)(bb + lane * 8);
  const float4 b1 = *(const float4*)(bb + lane * 8 + 4);
  float gv[8] = {g0.x, g0.y, g0.z, g0.w, g1.x, g1.y, g1.z, g1.w};
  float bv[8] = {b0.x, b0.y, b0.z, b0.w, b1.x, b1.y, b1.z, b1.w};
#pragma unroll
  for (int j = 0; j < 8; ++j)
    v[j] = (short)f2bf((x[j] - mu) * rstd * gv[j] + bv[j]);
  *(bf16x8*)p = v;
}

// ============ K3: final GEMM (bf16 MFMA): out = ln_att @ out_w + bias ============
__global__ __launch_bounds__(256) void out_gemm(const unsigned short* __restrict__ attb,
                                                const unsigned short* __restrict__ owt,
                                                const float* __restrict__ ob,
                                                float* __restrict__ outp) {
  __shared__ unsigned short As[128 * 72];
  __shared__ unsigned short Bs[128 * 72];
  const int t = threadIdx.x, lane = t & 63, wv = t >> 6;
  const int i = lane & 15, g = lane >> 4, kq = g * 8;
  const int wm = wv >> 1, wn = wv & 1;
  const int m0 = (blockIdx.x >> 2) * 128, n0 = (blockIdx.x & 3) * 128;
  const int sr = t >> 1, sko = (t & 1) * 32;
  const unsigned short* ag = attb + (size_t)(m0 + sr) * 512 + sko;
  const unsigned short* bg = owt + (size_t)(n0 + sr) * 512 + sko;
  f32x4 acc[4][4] = {};
  bf16x8 pa[4], pb[4];
#pragma unroll
  for (int p = 0; p < 4; ++p) {
    pa[p] = *(const bf16x8*)(ag + p * 8);
    pb[p] = *(const bf16x8*)(bg + p * 8);
  }
  for (int k0 = 0; k0 < 512; k0 += 64) {
    __syncthreads();
#pragma unroll
    for (int p = 0; p < 4; ++p) {
      *(bf16x8*)&As[sr * 72 + sko + p * 8] = pa[p];
      *(bf16x8*)&Bs[sr * 72 + sko + p * 8] = pb[p];
    }
    __syncthreads();
    if (k0 < 448) {
#pragma unroll
      for (int p = 0; p < 4; ++p) {
        pa[p] = *(const bf16x8*)(ag + k0 + 64 + p * 8);
        pb[p] = *(const bf16x8*)(bg + k0 + 64 + p * 8);
      }
    }
#pragma unroll
    for (int ks = 0; ks < 2; ++ks) {
      bf16x8 am[4], bn[4];
#pragma unroll
      for (int q = 0; q < 4; ++q) {
        am[q] = *(const bf16x8*)&As[(64 * wm + 16 * q + i) * 72 + ks * 32 + kq];
        bn[q] = *(const bf16x8*)&Bs[(64 * wn + 16 * q + i) * 72 + ks * 32 + kq];
      }
#pragma unroll
      for (int mi = 0; mi < 4; ++mi)
#pragma unroll
        for (int ni = 0; ni < 4; ++ni)
          acc[mi][ni] = __builtin_amdgcn_mfma_f32_16x16x32_bf16(am[mi], bn[ni], acc[mi][ni], 0, 0, 0);
    }
  }
#pragma unroll
  for (int ni = 0; ni < 4; ++ni) {
    float bv = ob[n0 + 64 * wn + 16 * ni + i];
#pragma unroll
    for (int mi = 0; mi < 4; ++mi)
#pragma unroll
      for (int r = 0; r < 4; ++r)
        outp[(size_t)(m0 + 64 * wm + 16 * mi + 4 * g + r) * 512 + n0 + 64 * wn +
             16 * ni + i] = acc[mi][ni][r] + bv;
  }
}

extern "C" void kernel_launch(void* const* d_in, const int* in_sizes, int n_in,
                              void* d_out, int out_size, void* d_ws,
                              size_t ws_size, hipStream_t stream) {
  const float* x = (const float*)d_in[0];
  const float* qkv_w = (const float*)d_in[1];
  const float* qkv_b = (const float*)d_in[2];
  const float* ln_g = (const float*)d_in[3];
  const float* ln_b = (const float*)d_in[4];
  const float* out_w = (const float*)d_in[5];
  const float* out_b = (const float*)d_in[6];
  float* out = (float*)d_out;

  char* w = (char*)d_ws;
  unsigned short* xb = (unsigned short*)w;                    // 33,554,432 B
  unsigned short* wt = (unsigned short*)(w + 33554432);       // 1,572,864 B
  unsigned short* owt = (unsigned short*)(w + 35127296);      // 524,288 B
  unsigned short* kvt = (unsigned short*)(w + 35651584);      // 1,048,576 B
  float* kmean = (float*)(w + 36700160);                      // 32,768 B
  char* R = w + 36732928;
  float* part = (float*)R;                    // 1024*8320*4 = 34,078,720 B
  unsigned short* attb = (unsigned short*)R;  // 33,554,432 B (aliases part; part dead by then)

  x_convert<<<8192, 256, 0, stream>>>(x, xb);
  w_transpose<<<256, 256, 0, stream>>>(qkv_w, out_w, wt, owt);
  kv_kernel<<<1024, 256, 0, stream>>>(xb, wt, qkv_b, part);
  kv_reduce<<<64, 256, 0, stream>>>(part, kvt, kmean);
  attn_kernel<<<2048, 256, 0, stream>>>(xb, wt, qkv_b, kvt, kmean, attb);
  ln_kernel<<<8192, 256, 0, stream>>>(attb, ln_g, ln_b);
  out_gemm<<<1024, 256, 0, stream>>>(attb, owt, out_b, out);
}

// Round 6
// 353.920 us; speedup vs baseline: 4.2886x; 1.0110x over previous
//
#include <hip/hip_runtime.h>
#include <math.h>

#define Bb 8
#define Nn 4096
#define Cc 512
#define Hh 8
#define PI4f 0.78539816339744830962f

using bf16x8 = __attribute__((ext_vector_type(8))) short;
using f32x4 = __attribute__((ext_vector_type(4))) float;

__device__ __forceinline__ unsigned short f2bf(float f) {
  unsigned u = __float_as_uint(f);
  u += 0x7FFFu + ((u >> 16) & 1u);
  return (unsigned short)(u >> 16);
}
__device__ __forceinline__ float bf2f(unsigned short h) {
  return __uint_as_float(((unsigned)h) << 16);
}
__device__ __forceinline__ float grp16_sum(float v) {
  v += __shfl_xor(v, 1);
  v += __shfl_xor(v, 2);
  v += __shfl_xor(v, 4);
  v += __shfl_xor(v, 8);
  return v;
}
__device__ __forceinline__ float wsum64(float v) {
#pragma unroll
  for (int m = 32; m >= 1; m >>= 1) v += __shfl_xor(v, m, 64);
  return v;
}
// tanh(x) = 1 - 2/(e^{2x}+1); ~1e-7 rel error
__device__ __forceinline__ float fast_tanh(float x) {
  float e = __expf(2.0f * x);
  return 1.0f - 2.0f / (e + 1.0f);
}
// async global->LDS, 16B per lane; LDS dest = wave-uniform base + lane*16
__device__ __forceinline__ void gload16(const unsigned short* g, unsigned short* l) {
  __builtin_amdgcn_global_load_lds(
      (const __attribute__((address_space(1))) void*)g,
      (__attribute__((address_space(3))) void*)l, 16, 0, 0);
}

// ============ convert x (fp32 -> bf16) ============
__global__ __launch_bounds__(256) void x_convert(const float* __restrict__ x,
                                                 unsigned short* __restrict__ xb) {
  size_t i = ((size_t)blockIdx.x * 256 + threadIdx.x) * 8;
  float4 a = *(const float4*)(x + i);
  float4 b = *(const float4*)(x + i + 4);
  int4 o;
  o.x = (int)f2bf(a.x) | ((int)f2bf(a.y) << 16);
  o.y = (int)f2bf(a.z) | ((int)f2bf(a.w) << 16);
  o.z = (int)f2bf(b.x) | ((int)f2bf(b.y) << 16);
  o.w = (int)f2bf(b.z) | ((int)f2bf(b.w) << 16);
  *(int4*)(xb + i) = o;
}

// ============ transpose qkv_w (512x1536) and out_w (512x512) -> bf16 [col][k] ============
__global__ __launch_bounds__(256) void w_transpose(const float* __restrict__ qkvw,
                                                   const float* __restrict__ outw,
                                                   unsigned short* __restrict__ wt,
                                                   unsigned short* __restrict__ owt) {
  __shared__ float tile[64][65];
  const int bid = blockIdx.x;
  const float* src;
  unsigned short* dst;
  int ldsrc, j0, k0;
  if (bid < 192) {
    src = qkvw; dst = wt; ldsrc = 1536;
    j0 = (bid % 24) * 64; k0 = (bid / 24) * 64;
  } else {
    int r = bid - 192;
    src = outw; dst = owt; ldsrc = 512;
    j0 = (r & 7) * 64; k0 = (r >> 3) * 64;
  }
  const int t = threadIdx.x;
  const int rr = t >> 4, cc = (t & 15) * 4;
#pragma unroll
  for (int it = 0; it < 4; ++it) {
    float4 v = *(const float4*)(src + (size_t)(k0 + rr + it * 16) * ldsrc + j0 + cc);
    tile[rr + it * 16][cc + 0] = v.x;
    tile[rr + it * 16][cc + 1] = v.y;
    tile[rr + it * 16][cc + 2] = v.z;
    tile[rr + it * 16][cc + 3] = v.w;
  }
  __syncthreads();
  const int j = t >> 2, kq = (t & 3) * 16;
  unsigned short u[16];
#pragma unroll
  for (int p = 0; p < 16; ++p) u[p] = f2bf(tile[kq + p][j]);
  int4 o;
  o.x = (int)u[0] | ((int)u[1] << 16);
  o.y = (int)u[2] | ((int)u[3] << 16);
  o.z = (int)u[4] | ((int)u[5] << 16);
  o.w = (int)u[6] | ((int)u[7] << 16);
  int4 o2;
  o2.x = (int)u[8] | ((int)u[9] << 16);
  o2.y = (int)u[10] | ((int)u[11] << 16);
  o2.z = (int)u[12] | ((int)u[13] << 16);
  o2.w = (int)u[14] | ((int)u[15] << 16);
  *(int4*)(dst + (size_t)(j0 + j) * 512 + k0 + kq) = o;
  *(int4*)(dst + (size_t)(j0 + j) * 512 + k0 + kq + 8) = o2;
}

// ============ qkv_gemm: qkv = x @ qkv_w + b -> bf16 [32768][1536] ============
// 128x128 tile, BK=64, global_load_lds staging (m97 structure). grid 3072.
__global__ __launch_bounds__(256) void qkv_gemm(const unsigned short* __restrict__ xb,
                                                const unsigned short* __restrict__ wt,
                                                const float* __restrict__ bias,
                                                unsigned short* __restrict__ qkvb) {
  __shared__ unsigned short As[128 * 64];
  __shared__ unsigned short Bs[128 * 64];
  const int t = threadIdx.x, lane = t & 63, wv = t >> 6;
  const int i = lane & 15, g = lane >> 4, kq = g * 8;
  const int wm = wv >> 1, wn = wv & 1;
  const int sbid = ((int)blockIdx.x & 7) * 384 + ((int)blockIdx.x >> 3);
  const int mt = sbid / 12, nt = sbid - mt * 12;
  const int m0 = mt * 128, n0 = nt * 128;
  const int lrow = lane >> 3, lchunk = (lane & 7) * 8;
  const unsigned short* agb = xb + (size_t)(m0 + 32 * wv + lrow) * 512 + lchunk;
  const unsigned short* bgb = wt + (size_t)(n0 + 32 * wv + lrow) * 512 + lchunk;
  unsigned short* asb = &As[(32 * wv) * 64];
  unsigned short* bsb = &Bs[(32 * wv) * 64];
  f32x4 acc[4][4] = {};
  for (int k0 = 0; k0 < 512; k0 += 64) {
    __syncthreads();
#pragma unroll
    for (int c = 0; c < 4; ++c) {
      gload16(agb + (size_t)(8 * c) * 512 + k0, asb + 8 * c * 64);
      gload16(bgb + (size_t)(8 * c) * 512 + k0, bsb + 8 * c * 64);
    }
    __syncthreads();
#pragma unroll
    for (int ks = 0; ks < 2; ++ks) {
      bf16x8 am[4], bn[4];
#pragma unroll
      for (int q = 0; q < 4; ++q) {
        am[q] = *(const bf16x8*)&As[(64 * wm + 16 * q + i) * 64 + ks * 32 + kq];
        bn[q] = *(const bf16x8*)&Bs[(64 * wn + 16 * q + i) * 64 + ks * 32 + kq];
      }
#pragma unroll
      for (int mi = 0; mi < 4; ++mi)
#pragma unroll
        for (int ni = 0; ni < 4; ++ni)
          acc[mi][ni] = __builtin_amdgcn_mfma_f32_16x16x32_bf16(am[mi], bn[ni], acc[mi][ni], 0, 0, 0);
    }
  }
#pragma unroll
  for (int ni = 0; ni < 4; ++ni) {
    const int col = n0 + 64 * wn + 16 * ni + i;
    const float bv = bias[col];
#pragma unroll
    for (int mi = 0; mi < 4; ++mi) {
      const size_t rowb = (size_t)(m0 + 64 * wm + 16 * mi + 4 * g) * 1536 + col;
#pragma unroll
      for (int r = 0; r < 4; ++r)
        qkvb[rowb + (size_t)r * 1536] = f2bf(acc[mi][ni][r] + bv);
    }
  }
}

// ============ kv_feat: feature map + kv/ksum accumulation (atomics) ============
// grid 1024: bh = bid>>4, chunk = bid&15 (256 rows = 2 tiles of 128)
__global__ __launch_bounds__(256) void kv_feat(const unsigned short* __restrict__ qkvb,
                                               float* __restrict__ kvacc,
                                               float* __restrict__ ksum) {
  __shared__ unsigned short kf_t[128 * 136];  // [f][n] bf16
  __shared__ unsigned short v_t[64 * 136];    // [d][n] bf16
  const int t = threadIdx.x, lane = t & 63, wv = t >> 6;
  const int i = lane & 15, g = lane >> 4, kq = g * 8;
  const int bh = (int)blockIdx.x >> 4, chunk = (int)blockIdx.x & 15;
  const int b = bh >> 3, h = bh & 7;
  const size_t rowbase = (size_t)b * Nn + chunk * 256;
  f32x4 kvf[2][4] = {};
  float ksc[4] = {0.f, 0.f, 0.f, 0.f}, kss[4] = {0.f, 0.f, 0.f, 0.f};
  for (int t2 = 0; t2 < 2; ++t2) {
#pragma unroll
    for (int mi = 0; mi < 2; ++mi) {
      float kx[4][4], vx[4][4];
#pragma unroll
      for (int r = 0; r < 4; ++r) {
        const unsigned short* rp =
            qkvb + (rowbase + t2 * 128 + 32 * wv + 16 * mi + 4 * g + r) * 1536 + h * 64 + i;
#pragma unroll
        for (int ni = 0; ni < 4; ++ni) {
          kx[ni][r] = bf2f(rp[512 + 16 * ni]);
          vx[ni][r] = bf2f(rp[1024 + 16 * ni]);
        }
      }
      float nrm[4];
#pragma unroll
      for (int r = 0; r < 4; ++r) {
        float s = kx[0][r] * kx[0][r] + kx[1][r] * kx[1][r] +
                  kx[2][r] * kx[2][r] + kx[3][r] * kx[3][r];
        nrm[r] = sqrtf(grp16_sum(s));
      }
#pragma unroll
      for (int ni = 0; ni < 4; ++ni)
#pragma unroll
        for (int r = 0; r < 4; ++r) {
          float k1 = kx[ni][r];
          float dk = fast_tanh(k1 / nrm[r] * 20.0f) * PI4f;
          float a3 = fabsf(k1);
          a3 = a3 * a3 * a3;
          float sn, cs;
          __sincosf(dk, &sn, &cs);
          float kc = a3 * cs, ksn = a3 * sn;
          ksc[ni] += kc;
          kss[ni] += ksn;
          const int nl = 32 * wv + 16 * mi + 4 * g + r;
          kf_t[(16 * ni + i) * 136 + nl] = f2bf(kc);
          kf_t[(64 + 16 * ni + i) * 136 + nl] = f2bf(ksn);
          v_t[(16 * ni + i) * 136 + nl] = f2bf(vx[ni][r]);
        }
    }
    __syncthreads();
    // kv += kf_t @ v_t^T over this 128-row tile; wave owns f-strip 32*wv
#pragma unroll
    for (int ks2 = 0; ks2 < 4; ++ks2) {
      bf16x8 a2[2], b2[4];
#pragma unroll
      for (int mi = 0; mi < 2; ++mi)
        a2[mi] = *(const bf16x8*)&kf_t[(32 * wv + 16 * mi + i) * 136 + ks2 * 32 + kq];
#pragma unroll
      for (int ni = 0; ni < 4; ++ni)
        b2[ni] = *(const bf16x8*)&v_t[(16 * ni + i) * 136 + ks2 * 32 + kq];
#pragma unroll
      for (int mi = 0; mi < 2; ++mi)
#pragma unroll
        for (int ni = 0; ni < 4; ++ni)
          kvf[mi][ni] = __builtin_amdgcn_mfma_f32_16x16x32_bf16(a2[mi], b2[ni], kvf[mi][ni], 0, 0, 0);
    }
    __syncthreads();
  }
  // atomic accumulation (raw sums; consumer applies 1/N)
#pragma unroll
  for (int mi = 0; mi < 2; ++mi)
#pragma unroll
    for (int ni = 0; ni < 4; ++ni)
#pragma unroll
      for (int r = 0; r < 4; ++r)
        atomicAdd(kvacc + (size_t)bh * 8192 +
                      (32 * wv + 16 * mi + 4 * g + r) * 64 + 16 * ni + i,
                  kvf[mi][ni][r]);
#pragma unroll
  for (int ni = 0; ni < 4; ++ni) {
    float c = ksc[ni];
    c += __shfl_xor(c, 16);
    c += __shfl_xor(c, 32);
    float s = kss[ni];
    s += __shfl_xor(s, 16);
    s += __shfl_xor(s, 32);
    if (lane < 16) {
      atomicAdd(ksum + bh * 128 + 16 * ni + lane, c);
      atomicAdd(ksum + bh * 128 + 64 + 16 * ni + lane, s);
    }
  }
}

// ============ attn_feat: qf/z + PV (MFMA) -> att bf16 ============
// grid 2048: bh = bid>>5, chunk = bid&31 (128 rows)
__global__ __launch_bounds__(256) void attn_feat(const unsigned short* __restrict__ qkvb,
                                                 const float* __restrict__ kvacc,
                                                 const float* __restrict__ ksum,
                                                 unsigned short* __restrict__ attb) {
  __shared__ unsigned short qf_t[128 * 136];  // [n][f]
  __shared__ unsigned short kv_s[64 * 136];   // [d][f]
  __shared__ float km[128];
  const int t = threadIdx.x, lane = t & 63, wv = t >> 6;
  const int i = lane & 15, g = lane >> 4, kq = g * 8;
  const int bh = (int)blockIdx.x >> 5, chunk = (int)blockIdx.x & 31;
  const int b = bh >> 3, h = bh & 7;
  const size_t row0 = (size_t)b * Nn + chunk * 128;
  const float invN = 1.0f / Nn;
  for (int idx = t; idx < 8192; idx += 256) {
    int f = idx >> 6, d = idx & 63;
    kv_s[d * 136 + f] = f2bf(kvacc[(size_t)bh * 8192 + idx] * invN);
  }
  if (t < 128) km[t] = ksum[bh * 128 + t] * invN;
  // load q fragments while staging is in flight
  float qx[2][4][4];
#pragma unroll
  for (int mi = 0; mi < 2; ++mi)
#pragma unroll
    for (int r = 0; r < 4; ++r) {
      const unsigned short* rp =
          qkvb + (row0 + 32 * wv + 16 * mi + 4 * g + r) * 1536 + h * 64 + i;
#pragma unroll
      for (int ni = 0; ni < 4; ++ni) qx[mi][ni][r] = bf2f(rp[16 * ni]);
    }
  __syncthreads();
  float z[2][4];
#pragma unroll
  for (int mi = 0; mi < 2; ++mi) {
    float nrm[4];
#pragma unroll
    for (int r = 0; r < 4; ++r) {
      float s = qx[mi][0][r] * qx[mi][0][r] + qx[mi][1][r] * qx[mi][1][r] +
                qx[mi][2][r] * qx[mi][2][r] + qx[mi][3][r] * qx[mi][3][r];
      nrm[r] = sqrtf(grp16_sum(s));
    }
#pragma unroll
    for (int r = 0; r < 4; ++r) {
      float pwr = 1.5f * (0.5f + fast_tanh(nrm[r]));
      float dp = 0.f;
      const int nl = 32 * wv + 16 * mi + 4 * g + r;
#pragma unroll
      for (int ni = 0; ni < 4; ++ni) {
        float q = qx[mi][ni][r];
        float qt = q / nrm[r];
        float dq = fast_tanh(qt * 20.0f) * PI4f;
        float qtp = exp2f(pwr * __log2f(qt * qt));
        float sn, cs;
        __sincosf(dq, &sn, &cs);
        float qc = qtp * cs, qs = qtp * sn;
        dp += qc * km[16 * ni + i] + qs * km[64 + 16 * ni + i];
        qf_t[nl * 136 + 16 * ni + i] = f2bf(qc);
        qf_t[nl * 136 + 64 + 16 * ni + i] = f2bf(qs);
      }
      z[mi][r] = 1.0f / (grp16_sum(dp) + 1e-6f);
    }
  }
  __syncthreads();
  f32x4 pacc[2][4] = {};
#pragma unroll
  for (int ks2 = 0; ks2 < 4; ++ks2) {
    bf16x8 a2[2], b2[4];
#pragma unroll
    for (int mi = 0; mi < 2; ++mi)
      a2[mi] = *(const bf16x8*)&qf_t[(32 * wv + 16 * mi + i) * 136 + ks2 * 32 + kq];
#pragma unroll
    for (int ni = 0; ni < 4; ++ni)
      b2[ni] = *(const bf16x8*)&kv_s[(16 * ni + i) * 136 + ks2 * 32 + kq];
#pragma unroll
    for (int mi = 0; mi < 2; ++mi)
#pragma unroll
      for (int ni = 0; ni < 4; ++ni)
        pacc[mi][ni] = __builtin_amdgcn_mfma_f32_16x16x32_bf16(a2[mi], b2[ni], pacc[mi][ni], 0, 0, 0);
  }
#pragma unroll
  for (int mi = 0; mi < 2; ++mi)
#pragma unroll
    for (int ni = 0; ni < 4; ++ni)
#pragma unroll
      for (int r = 0; r < 4; ++r)
        attb[(row0 + 32 * wv + 16 * mi + 4 * g + r) * 512 + h * 64 + 16 * ni + i] =
            f2bf(pacc[mi][ni][r] * z[mi][r]);
}

// ============ in-place LayerNorm on bf16 att ============
__global__ __launch_bounds__(256) void ln_kernel(unsigned short* __restrict__ attb,
                                                 const float* __restrict__ gg,
                                                 const float* __restrict__ bb) {
  const int lane = threadIdx.x & 63, wv = threadIdx.x >> 6;
  const size_t row = (size_t)blockIdx.x * 4 + wv;
  unsigned short* p = attb + row * 512 + lane * 8;
  bf16x8 v = *(bf16x8*)p;
  float x[8];
#pragma unroll
  for (int j = 0; j < 8; ++j) x[j] = bf2f((unsigned short)v[j]);
  float s = 0.f;
#pragma unroll
  for (int j = 0; j < 8; ++j) s += x[j];
  const float mu = wsum64(s) * (1.0f / 512.0f);
  float sq = 0.f;
#pragma unroll
  for (int j = 0; j < 8; ++j) {
    float d = x[j] - mu;
    sq += d * d;
  }
  const float rstd = rsqrtf(wsum64(sq) * (1.0f / 512.0f) + 1e-5f);
  const float4 g0 = *(const float4*)(gg + lane * 8);
  const float4 g1 = *(const float4*)(gg + lane * 8 + 4);
  const float4 b0 = *(const float4*)(bb + lane * 8);
  const float4 b1 = *(const float4*)(bb + lane * 8 + 4);
  float gv[8] = {g0.x, g0.y, g0.z, g0.w, g1.x, g1.y, g1.z, g1.w};
  float bv[8] = {b0.x, b0.y, b0.z, b0.w, b1.x, b1.y, b1.z, b1.w};
#pragma unroll
  for (int j = 0; j < 8; ++j)
    v[j] = (short)f2bf((x[j] - mu) * rstd * gv[j] + bv[j]);
  *(bf16x8*)p = v;
}

// ============ out_gemm: out = ln_att @ out_w + bias (fp32 out, gload_lds) ============
__global__ __launch_bounds__(256) void out_gemm(const unsigned short* __restrict__ attb,
                                                const unsigned short* __restrict__ owt,
                                                const float* __restrict__ ob,
                                                float* __restrict__ outp) {
  __shared__ unsigned short As[128 * 64];
  __shared__ unsigned short Bs[128 * 64];
  const int t = threadIdx.x, lane = t & 63, wv = t >> 6;
  const int i = lane & 15, g = lane >> 4, kq = g * 8;
  const int wm = wv >> 1, wn = wv & 1;
  const int sbid = ((int)blockIdx.x & 7) * 128 + ((int)blockIdx.x >> 3);
  const int m0 = (sbid >> 2) * 128, n0 = (sbid & 3) * 128;
  const int lrow = lane >> 3, lchunk = (lane & 7) * 8;
  const unsigned short* agb = attb + (size_t)(m0 + 32 * wv + lrow) * 512 + lchunk;
  const unsigned short* bgb = owt + (size_t)(n0 + 32 * wv + lrow) * 512 + lchunk;
  unsigned short* asb = &As[(32 * wv) * 64];
  unsigned short* bsb = &Bs[(32 * wv) * 64];
  f32x4 acc[4][4] = {};
  for (int k0 = 0; k0 < 512; k0 += 64) {
    __syncthreads();
#pragma unroll
    for (int c = 0; c < 4; ++c) {
      gload16(agb + (size_t)(8 * c) * 512 + k0, asb + 8 * c * 64);
      gload16(bgb + (size_t)(8 * c) * 512 + k0, bsb + 8 * c * 64);
    }
    __syncthreads();
#pragma unroll
    for (int ks = 0; ks < 2; ++ks) {
      bf16x8 am[4], bn[4];
#pragma unroll
      for (int q = 0; q < 4; ++q) {
        am[q] = *(const bf16x8*)&As[(64 * wm + 16 * q + i) * 64 + ks * 32 + kq];
        bn[q] = *(const bf16x8*)&Bs[(64 * wn + 16 * q + i) * 64 + ks * 32 + kq];
      }
#pragma unroll
      for (int mi = 0; mi < 4; ++mi)
#pragma unroll
        for (int ni = 0; ni < 4; ++ni)
          acc[mi][ni] = __builtin_amdgcn_mfma_f32_16x16x32_bf16(am[mi], bn[ni], acc[mi][ni], 0, 0, 0);
    }
  }
#pragma unroll
  for (int ni = 0; ni < 4; ++ni) {
    const float bv = ob[n0 + 64 * wn + 16 * ni + i];
#pragma unroll
    for (int mi = 0; mi < 4; ++mi)
#pragma unroll
      for (int r = 0; r < 4; ++r)
        outp[(size_t)(m0 + 64 * wm + 16 * mi + 4 * g + r) * 512 + n0 + 64 * wn +
             16 * ni + i] = acc[mi][ni][r] + bv;
  }
}

extern "C" void kernel_launch(void* const* d_in, const int* in_sizes, int n_in,
                              void* d_out, int out_size, void* d_ws,
                              size_t ws_size, hipStream_t stream) {
  const float* x = (const float*)d_in[0];
  const float* qkv_w = (const float*)d_in[1];
  const float* qkv_b = (const float*)d_in[2];
  const float* ln_g = (const float*)d_in[3];
  const float* ln_b = (const float*)d_in[4];
  const float* out_w = (const float*)d_in[5];
  const float* out_b = (const float*)d_in[6];
  float* out = (float*)d_out;

  char* w = (char*)d_ws;
  unsigned short* xb = (unsigned short*)w;                 // 33,554,432 B
  unsigned short* attb = xb;                               // alias (xb dead after qkv_gemm)
  unsigned short* wt = (unsigned short*)(w + 33554432);    // 1,572,864 B
  unsigned short* owt = (unsigned short*)(w + 35127296);   // 524,288 B
  float* kvacc = (float*)(w + 35651584);                   // 2,097,152 B
  float* ksum = (float*)(w + 37748736);                    // 32,768 B
  unsigned short* qkvb = (unsigned short*)(w + 37781504);  // 100,663,296 B (end ~132 MB)

  hipMemsetAsync(kvacc, 0, 2097152 + 32768, stream);
  x_convert<<<8192, 256, 0, stream>>>(x, xb);
  w_transpose<<<256, 256, 0, stream>>>(qkv_w, out_w, wt, owt);
  qkv_gemm<<<3072, 256, 0, stream>>>(xb, wt, qkv_b, qkvb);
  kv_feat<<<1024, 256, 0, stream>>>(qkvb, kvacc, ksum);
  attn_feat<<<2048, 256, 0, stream>>>(qkvb, kvacc, ksum, attb);
  ln_kernel<<<8192, 256, 0, stream>>>(attb, ln_g, ln_b);
  out_gemm<<<1024, 256, 0, stream>>>(attb, owt, out_b, out);
}